// Round 1
// baseline (1328.011 us; speedup 1.0000x reference)
//
#include <hip/hip_runtime.h>
#include <hip/hip_bf16.h>
#include <math.h>

typedef __attribute__((ext_vector_type(8))) short bf16x8;
typedef __attribute__((ext_vector_type(4))) float f32x4;
using bf16 = __hip_bfloat16;

constexpr int NN   = 2048;
constexpr int KO   = 8;
constexpr int IH   = 128, IW = 128;
constexpr int GS   = 50;
constexpr int HIDD = 256;
// rin: [enc 0..100 | zwl 100..103 | pzw 103..106 | zwhatl 106..156 | pzwhat 156..206 | hl 206..462 | h_r 462..718 | pad..768]
constexpr int RIN_LD = 768;
// tin: [g2 0..2500 | zw 2500..2503 | pzw 2503..2506 | zwhatl 2506..2556 | pzwhat 2556..2606 | hl 2606..2862 | h_r2 2862..3118 | pad..3136]
constexpr int TIN_LD = 3136;
constexpr int G1_LD  = 2560;
constexpr int GROWS  = 64;        // LDS-staged image rows for glimpse1 (32 KB)
constexpr int GROWS2 = 48;        // LDS-staged image rows for glimpse2 (24 KB; zw scale is small)

__device__ __forceinline__ float sigm(float x) { return 1.f/(1.f+expf(-x)); }

// ================= MFMA GEMM v3 + XCD swizzle: 64x64 tile, BK=64, 2 blocks/CU ==================
template<int OUT_BF16, int RELU>
__global__ __launch_bounds__(256, 2) void mfma_gemm(
    const bf16* __restrict__ A, int lda, int Kd,
    const bf16* __restrict__ Wt, int ldw, int M,
    const float* __restrict__ b1, const float* __restrict__ b2,
    void* __restrict__ Cout, int ldc, int nxb)
{
    __shared__ bf16x8 As16[512];
    __shared__ bf16x8 Bs16[512];
    const int b    = blockIdx.x;
    const int xcd  = b & 7;
    const int t    = b >> 3;
    const int n0   = (xcd + 8*(t / nxb))*64;
    const int m0   = (t % nxb)*64;
    const int tid  = threadIdx.x;
    const int wave = tid>>6, lane = tid&63;
    const int wy   = wave>>1, wx = wave&1;

    const int row = tid>>2, part = tid&3;
    const bf16* Ap = A + (size_t)(n0+row)*lda + part*8;
    const int   wm = m0 + row;
    const bool  wok = wm < M;
    const bf16* Wp = Wt + (size_t)(wok ? wm : 0)*ldw + part*8;
    const int dst0 = ((row>>4)*2+0)*64 + part*16 + (row&15);
    const int dst1 = dst0 + 64;

    f32x4 acc[2][2] = {};
    const bf16x8 z8 = {};
    bf16x8 pa0 = *(const bf16x8*)Ap;
    bf16x8 pa1 = *(const bf16x8*)(Ap + 32);
    bf16x8 pw0 = *(const bf16x8*)Wp;
    bf16x8 pw1 = *(const bf16x8*)(Wp + 32);

    for (int k0 = 0; k0 < Kd; k0 += 64) {
        __syncthreads();
        As16[dst0] = pa0;
        As16[dst1] = pa1;
        Bs16[dst0] = wok ? pw0 : z8;
        Bs16[dst1] = wok ? pw1 : z8;
        __syncthreads();
        if (k0 + 64 < Kd) {
            pa0 = *(const bf16x8*)(Ap + k0 + 64);
            pa1 = *(const bf16x8*)(Ap + k0 + 96);
            pw0 = *(const bf16x8*)(Wp + k0 + 64);
            pw1 = *(const bf16x8*)(Wp + k0 + 96);
        }
        bf16x8 av[2][2], bv[2][2];
        #pragma unroll
        for (int i=0;i<2;i++)
            #pragma unroll
            for (int h=0;h<2;h++) av[i][h] = As16[((wy*2+i)*2+h)*64 + lane];
        #pragma unroll
        for (int j=0;j<2;j++)
            #pragma unroll
            for (int h=0;h<2;h++) bv[j][h] = Bs16[((wx*2+j)*2+h)*64 + lane];
        #pragma unroll
        for (int h=0;h<2;h++)
            #pragma unroll
            for (int i=0;i<2;i++)
                #pragma unroll
                for (int j=0;j<2;j++)
                    acc[i][j] = __builtin_amdgcn_mfma_f32_16x16x32_bf16(av[i][h], bv[j][h], acc[i][j], 0, 0, 0);
    }

    const int q = lane>>4, r = lane&15;
    #pragma unroll
    for (int j=0;j<2;j++) {
        int col = m0 + wx*32 + j*16 + r;
        if (col < M) {
            float bias = 0.f;
            if (b1) bias += b1[col];
            if (b2) bias += b2[col];
            #pragma unroll
            for (int i=0;i<2;i++) {
                #pragma unroll
                for (int reg=0;reg<4;reg++) {
                    float v = acc[i][j][reg] + bias;
                    if (RELU) v = fmaxf(v, 0.f);
                    size_t idx = (size_t)(n0 + wy*32 + i*16 + q*4 + reg)*ldc + col;
                    if (OUT_BF16) ((bf16*)Cout)[idx] = __float2bfloat16(v);
                    else          ((float*)Cout)[idx] = v;
                }
            }
        }
    }
}

// ================= glimpse point math (global-gather path) =================
__device__ __forceinline__ void glimpse_points_global(const float* __restrict__ im,
                                                      float s, float tx, float ty,
                                                      bf16* __restrict__ drow) {
    const float GXS = 2.0f/49.0f;
    const float txp = tx + 1.0f, typ = ty + 1.0f;
    for (int p2 = threadIdx.x; p2 < 1250; p2 += 256) {
        int i = p2 / 25, j = (p2 - i*25)*2;
        float gy  = fmaf((float)i, GXS, -1.0f);
        float py  = fmaf(s, gy, typ)*63.5f;
        float y0f = floorf(py); float fy = py - y0f; int y0 = (int)y0f;
        float wy0 = ((unsigned)y0     < 128u) ? (1.f - fy) : 0.f;
        float wy1 = ((unsigned)(y0+1) < 128u) ? fy         : 0.f;
        const float* r0 = im + min(max(y0,  0),127)*IW;
        const float* r1 = im + min(max(y0+1,0),127)*IW;
        float gxa = fmaf((float)j, GXS, -1.0f);
        float pxa = fmaf(s, gxa, txp)*63.5f;
        float xa0f = floorf(pxa); float fa = pxa - xa0f; int xa0 = (int)xa0f;
        float wa0 = ((unsigned)xa0     < 128u) ? (1.f - fa) : 0.f;
        float wa1 = ((unsigned)(xa0+1) < 128u) ? fa         : 0.f;
        int xa0c = min(max(xa0,  0),127), xa1c = min(max(xa0+1,0),127);
        float gxb = fmaf((float)(j+1), GXS, -1.0f);
        float pxb = fmaf(s, gxb, txp)*63.5f;
        float xb0f = floorf(pxb); float fb = pxb - xb0f; int xb0 = (int)xb0f;
        float wb0 = ((unsigned)xb0     < 128u) ? (1.f - fb) : 0.f;
        float wb1 = ((unsigned)(xb0+1) < 128u) ? fb         : 0.f;
        int xb0c = min(max(xb0,  0),127), xb1c = min(max(xb0+1,0),127);

        float va = fmaf(wy1, fmaf(wa0, r1[xa0c], wa1*r1[xa1c]),
                   wy0 *     fmaf(wa0, r0[xa0c], wa1*r0[xa1c]));
        float vb = fmaf(wy1, fmaf(wb0, r1[xb0c], wb1*r1[xb1c]),
                   wy0 *     fmaf(wb0, r0[xb0c], wb1*r0[xb1c]));

        bf16 b0 = __float2bfloat16(va), b1 = __float2bfloat16(vb);
        unsigned short u0, u1;
        __builtin_memcpy(&u0, &b0, 2); __builtin_memcpy(&u1, &b1, 2);
        *(unsigned int*)(drow + i*GS + j) = (unsigned)u0 | ((unsigned)u1 << 16);
    }
}

// ================= glimpse point math (LDS row-staged path) =================
// rows[] holds image rows [ylo .. ylo+nrows-1], contiguous, IW floats each.
__device__ __forceinline__ void glimpse_points_lds(const float* __restrict__ rows,
                                                   int ylo, int nrows,
                                                   float s, float tx, float ty,
                                                   bf16* __restrict__ drow) {
    const float GXS = 2.0f/49.0f;
    const float txp = tx + 1.0f, typ = ty + 1.0f;
    for (int p2 = threadIdx.x; p2 < 1250; p2 += 256) {
        int i = p2 / 25, j = (p2 - i*25)*2;
        float gy  = fmaf((float)i, GXS, -1.0f);
        float py  = fmaf(s, gy, typ)*63.5f;
        float y0f = floorf(py); float fy = py - y0f; int y0 = (int)y0f;
        float wy0 = ((unsigned)y0     < 128u) ? (1.f - fy) : 0.f;
        float wy1 = ((unsigned)(y0+1) < 128u) ? fy         : 0.f;
        const float* r0 = rows + min(max(y0-ylo,   0), nrows-1)*IW;
        const float* r1 = rows + min(max(y0+1-ylo, 0), nrows-1)*IW;
        float gxa = fmaf((float)j, GXS, -1.0f);
        float pxa = fmaf(s, gxa, txp)*63.5f;
        float xa0f = floorf(pxa); float fa = pxa - xa0f; int xa0 = (int)xa0f;
        float wa0 = ((unsigned)xa0     < 128u) ? (1.f - fa) : 0.f;
        float wa1 = ((unsigned)(xa0+1) < 128u) ? fa         : 0.f;
        int xa0c = min(max(xa0,  0),127), xa1c = min(max(xa0+1,0),127);
        float gxb = fmaf((float)(j+1), GXS, -1.0f);
        float pxb = fmaf(s, gxb, txp)*63.5f;
        float xb0f = floorf(pxb); float fb = pxb - xb0f; int xb0 = (int)xb0f;
        float wb0 = ((unsigned)xb0     < 128u) ? (1.f - fb) : 0.f;
        float wb1 = ((unsigned)(xb0+1) < 128u) ? fb         : 0.f;
        int xb0c = min(max(xb0,  0),127), xb1c = min(max(xb0+1,0),127);
        float va = fmaf(wy1, fmaf(wa0, r1[xa0c], wa1*r1[xa1c]),
                   wy0 *     fmaf(wa0, r0[xa0c], wa1*r0[xa1c]));
        float vb = fmaf(wy1, fmaf(wb0, r1[xb0c], wb1*r1[xb1c]),
                   wy0 *     fmaf(wb0, r0[xb0c], wb1*r0[xb1c]));
        bf16 b0 = __float2bfloat16(va), b1 = __float2bfloat16(vb);
        unsigned short u0, u1;
        __builtin_memcpy(&u0, &b0, 2); __builtin_memcpy(&u1, &b1, 2);
        *(unsigned int*)(drow + i*GS + j) = (unsigned)u0 | ((unsigned)u1 << 16);
    }
}

// ========= glimpse1 (LDS row-staged, fallback global) + rin static-col fill, fused =========
__global__ __launch_bounds__(256) void glimpse_batch(const float* __restrict__ img,
                                                     const float* __restrict__ z,
                                                     bf16* __restrict__ dst, int ldd,
                                                     bf16* __restrict__ rin,
                                                     const float* __restrict__ z_where_last,
                                                     const float* __restrict__ z_what_last,
                                                     const float* __restrict__ hidden_last,
                                                     int cbase) {
    __shared__ float rows[GROWS*IW];
    int b = blockIdx.x;
    int n = b & (NN-1);
    int sl = b >> 11;
    const float* im = img + (size_t)n*IH*IW;
    float s  = z[b*3+0];
    float tx = z[b*3+1];
    float ty = z[b*3+2];
    bf16* drow = dst + (size_t)b*ldd;

    const float txp = tx + 1.0f, typ = ty + 1.0f;
    float pyA = fmaf(s, -1.f, typ)*63.5f;
    float pyB = fmaf(s,  1.f, typ)*63.5f;
    int ylo = (int)floorf(fminf(pyA, pyB));
    int yhi = (int)floorf(fmaxf(pyA, pyB)) + 1;
    ylo = min(max(ylo, 0), 127);
    yhi = min(max(yhi, 0), 127);
    int nrows = yhi - ylo + 1;

    if (nrows <= GROWS) {
        const float4* src = (const float4*)(im + ylo*IW);
        float4* d4 = (float4*)rows;
        int tot = nrows*(IW/4);
        for (int t = threadIdx.x; t < tot; t += 256) d4[t] = src[t];
        __syncthreads();
        glimpse_points_lds(rows, ylo, nrows, s, tx, ty, drow);
    } else {
        glimpse_points_global(im, s, tx, ty, drow);
    }

    // fused rin static-col fill: zwl(100..103), zwhatl(106..156), hl(206..462)
    int k = cbase + sl;
    bf16* rrow = rin + (size_t)b*RIN_LD;
    for (int c = threadIdx.x; c < 309; c += 256) {
        float v; int col;
        if (c < 3)       { col = 100 + c;      v = z_where_last[((size_t)n*KO + k)*3 + c]; }
        else if (c < 53) { col = 106 + (c-3);  v = z_what_last[((size_t)n*KO + k)*50 + (c-3)]; }
        else             { col = 206 + (c-53); v = hidden_last[((size_t)n*KO + k)*HIDD + (c-53)]; }
        rrow[col] = __float2bfloat16(v);
    }
}

// ===== merged per-step kernel: rel LSTM elementwise + zw linear + glimpse2 + tin fill =====
// glimpse2 now uses LDS row staging (region is small: zw comes from 0.02-scale
// weights, so |s| ~ 0.1-0.25 -> ~15-35 rows). Fallback to global gather if > GROWS2.
__global__ __launch_bounds__(256) void rel_glimpse2(
    const float* __restrict__ gates, float* __restrict__ h_r, float* __restrict__ c_r,
    const float* __restrict__ z_where_last,
    const float* __restrict__ Wm_wh, const float* __restrict__ bm_wh,
    float* __restrict__ zw_cur, float* __restrict__ out_zwhere,
    bf16* __restrict__ rin_next, bf16* __restrict__ tin,
    const float* __restrict__ img,
    const float* __restrict__ zw_prev, const float* __restrict__ zwhat_prev,
    const float* __restrict__ z_what_last, const float* __restrict__ hidden_last, int k)
{
    __shared__ float rows[GROWS2*IW];
    __shared__ float hs[256];
    __shared__ float zws[3];
    int n = blockIdx.x, j = threadIdx.x;
    const float* g = gates + (size_t)n*1024;
    float ig = sigm(g[j]);
    float fg = sigm(g[256+j]);
    float gg = tanhf(g[512+j]);
    float og = sigm(g[768+j]);
    int cidx = n*256 + j;
    float c2 = fg*c_r[cidx] + ig*gg;
    float hv = og*tanhf(c2);
    c_r[cidx] = c2;
    h_r[cidx] = hv;
    hs[j] = hv;
    bf16 hb = __float2bfloat16(hv);
    rin_next[(size_t)n*RIN_LD + 462 + j] = hb;
    bf16* trow = tin + (size_t)n*TIN_LD;
    trow[2862 + j] = hb;
    __syncthreads();
    int w = j >> 6, lane = j & 63;
    if (w < 3) {
        const float* wt = Wm_wh + w*259;
        float sa = 0.f;
        for (int i = lane; i < 256; i += 64) sa = fmaf(hs[i], wt[3+i], sa);
        #pragma unroll
        for (int off = 32; off; off >>= 1) sa += __shfl_down(sa, off);
        if (lane == 0) {
            const float* zwl = z_where_last + ((size_t)n*KO + k)*3;
            float acc = bm_wh[w] + sa;
            for (int i = 0; i < 3; i++) acc = fmaf(zwl[i], wt[i], acc);
            zws[w] = acc;
            zw_cur[n*3+w] = acc;
            out_zwhere[((size_t)n*KO + k)*3 + w] = acc;
            bf16 ab = __float2bfloat16(acc);
            rin_next[(size_t)n*RIN_LD + 103 + w] = ab;
            trow[2500 + w] = ab;
        }
    }
    __syncthreads();
    float s = zws[0], tx = zws[1], ty = zws[2];
    const float* im = img + (size_t)n*IH*IW;
    {
        const float typ = ty + 1.0f;
        float pyA = fmaf(s, -1.f, typ)*63.5f;
        float pyB = fmaf(s,  1.f, typ)*63.5f;
        int ylo = (int)floorf(fminf(pyA, pyB));
        int yhi = (int)floorf(fmaxf(pyA, pyB)) + 1;
        ylo = min(max(ylo, 0), 127);
        yhi = min(max(yhi, 0), 127);
        int nrows = yhi - ylo + 1;
        if (nrows <= GROWS2) {
            const float4* src = (const float4*)(im + ylo*IW);
            float4* d4 = (float4*)rows;
            int tot = nrows*(IW/4);
            for (int t = threadIdx.x; t < tot; t += 256) d4[t] = src[t];
            __syncthreads();
            glimpse_points_lds(rows, ylo, nrows, s, tx, ty, trow);
        } else {
            glimpse_points_global(im, s, tx, ty, trow);
        }
    }
    for (int c = 3 + j; c < 362; c += 256) {
        float v;
        if      (c <   6) v = zw_prev[n*3 + c-3];
        else if (c <  56) v = z_what_last[((size_t)n*KO + k)*50 + c-6];
        else if (c < 106) v = zwhat_prev[n*50 + c-56];
        else              v = hidden_last[((size_t)n*KO + k)*HIDD + c-106];
        trow[2500 + c] = __float2bfloat16(v);
    }
}

// ================= small / preamble kernels =================
__global__ void zero_f32(float* __restrict__ p, int n) {
    int i = blockIdx.x*blockDim.x + threadIdx.x;
    if (i < n) p[i] = 0.f;
}

__global__ void repack_w(const float* __restrict__ s1, int K1,
                         const float* __restrict__ s2, int K2,
                         bf16* __restrict__ dst, int ldd, int M) {
    int gid = blockIdx.x*blockDim.x + threadIdx.x;
    if (gid >= M*ldd) return;
    int m = gid / ldd, c = gid - m*ldd;
    float v = 0.f;
    if (c < K1)           v = s1[(size_t)m*K1 + c];
    else if (c < K1+K2)   v = s2[(size_t)m*K2 + (c-K1)];
    dst[gid] = __float2bfloat16(v);
}

__global__ __launch_bounds__(256) void zwb_all_v2(const float* __restrict__ hidden_last,
                                                  const float* __restrict__ z_where_last,
                                                  const float* __restrict__ Wl, const float* __restrict__ bl,
                                                  float* __restrict__ zwb_all) {
    __shared__ float wls[768];
    for (int i = threadIdx.x; i < 768; i += 256) wls[i] = Wl[i];
    __syncthreads();
    int wv = threadIdx.x>>6, lane = threadIdx.x&63;
    int row = blockIdx.x*4 + wv;
    int s = row >> 11, n = row & (NN-1);
    const float* hl = hidden_last + ((size_t)n*KO + s)*HIDD;
    float4 h4 = *(const float4*)(hl + lane*4);
    float s0=0.f, s1=0.f, s2=0.f;
    #pragma unroll
    for (int r4=0;r4<4;r4++) {
        float hv = ((const float*)&h4)[r4];
        int i = lane*4 + r4;
        s0 = fmaf(hv, wls[i],     s0);
        s1 = fmaf(hv, wls[256+i], s1);
        s2 = fmaf(hv, wls[512+i], s2);
    }
    #pragma unroll
    for (int off=32; off; off>>=1) {
        s0 += __shfl_down(s0,off); s1 += __shfl_down(s1,off); s2 += __shfl_down(s2,off);
    }
    if (lane == 0) {
        const float* zwl = z_where_last + ((size_t)n*KO + s)*3;
        zwb_all[row*3+0] = fmaxf(s0+bl[0],0.f) + zwl[0];
        zwb_all[row*3+1] = fmaxf(s1+bl[1],0.f) + zwl[1];
        zwb_all[row*3+2] = fmaxf(s2+bl[2],0.f) + zwl[2];
    }
}

__global__ void zero_rin_carry(bf16* __restrict__ rin0) {
    int gid = blockIdx.x*blockDim.x + threadIdx.x;
    if (gid >= NN*309) return;
    int c = gid % 309, n = gid/309;
    int col = (c < 3) ? 103+c : ((c < 53) ? 156+(c-3) : 462+(c-53));
    rin0[(size_t)n*RIN_LD + col] = __float2bfloat16(0.f);
}

// ================= tem LSTM + zwhat + pres (block per n) =================
__global__ __launch_bounds__(256) void tem_fused(
    const float* __restrict__ gates, const float* __restrict__ c_r, const float* __restrict__ h_r,
    const float* __restrict__ z_what_last,
    const float* __restrict__ Wm_wt, const float* __restrict__ bm_wt,
    const float* __restrict__ Wm_pr, const float* __restrict__ bm_pr,
    const float* __restrict__ Ws_pr, const float* __restrict__ bs_pr,
    const float* __restrict__ zw_cur, const float* __restrict__ z_pres_last,
    float* __restrict__ zwhat_cur, float* __restrict__ out_zwhat,
    float* __restrict__ out_htemp, float* __restrict__ out_zpres,
    bf16* __restrict__ rin_next, int k)
{
    __shared__ float L[615];
    int n = blockIdx.x, j = threadIdx.x;
    const float* g = gates + (size_t)n*1024;
    float ig = sigm(g[j]);
    float fg = sigm(g[256+j]);
    float gg = tanhf(g[512+j]);
    float og = sigm(g[768+j]);
    float c2 = fg*c_r[n*256+j] + ig*gg;
    float hv = og*tanhf(c2);
    out_htemp[((size_t)n*KO + k)*HIDD + j] = hv;
    L[309+j] = hv;
    L[53+j]  = h_r[n*256+j];
    if (j < 50)      L[j]  = z_what_last[((size_t)n*KO + k)*50 + j];
    else if (j < 53) L[j]  = zw_cur[n*3 + (j-50)];
    __syncthreads();
    if (j < 200) {
        int m = j >> 2, part = j & 3;
        const float* wt = Wm_wt + m*562;
        float s = 0.f;
        for (int i = part; i < 562; i += 4) {
            float v = (i < 50) ? L[i] : L[i+3];
            s = fmaf(v, wt[i], s);
        }
        s += __shfl_down(s, 2);
        s += __shfl_down(s, 1);
        if (part == 0) {
            float acc = s + bm_wt[m];
            zwhat_cur[n*50+m] = acc;
            out_zwhat[((size_t)n*KO + k)*50 + m] = acc;
            rin_next[(size_t)n*RIN_LD + 156 + m] = __float2bfloat16(acc);
            L[565+m] = acc;
        }
    }
    __syncthreads();
    if (j < 64) {
        float s1 = 0.f, s2 = 0.f;
        for (int i = j; i < 565; i += 64) {
            float v = (i < 50) ? L[565+i] : L[i];
            s1 = fmaf(v, Wm_pr[i], s1);
            s2 = fmaf(v, Ws_pr[i], s2);
        }
        #pragma unroll
        for (int off = 32; off; off >>= 1) { s1 += __shfl_down(s1,off); s2 += __shfl_down(s2,off); }
        if (j == 0) {
            float p = sigm(s1 + bm_pr[0]) * sigm(s2 + bs_pr[0]);
            out_zpres[(size_t)n*KO + k] = p * z_pres_last[(size_t)n*KO + k];
        }
    }
}

extern "C" void kernel_launch(void* const* d_in, const int* in_sizes, int n_in,
                              void* d_out, int out_size, void* d_ws, size_t ws_size,
                              hipStream_t stream) {
    (void)in_sizes; (void)n_in; (void)out_size;
    const float* img          = (const float*)d_in[0];
    const float* z_what_last  = (const float*)d_in[1];
    const float* z_where_last = (const float*)d_in[2];
    const float* z_pres_last  = (const float*)d_in[3];
    const float* hidden_last  = (const float*)d_in[4];
    const float* W_loca = (const float*)d_in[5];
    const float* b_loca = (const float*)d_in[6];
    const float* Wg     = (const float*)d_in[7];
    const float* bg     = (const float*)d_in[8];
    const float* Wih_rel = (const float*)d_in[9];
    const float* Whh_rel = (const float*)d_in[10];
    const float* bih_rel = (const float*)d_in[11];
    const float* bhh_rel = (const float*)d_in[12];
    const float* Wih_tem = (const float*)d_in[13];
    const float* Whh_tem = (const float*)d_in[14];
    const float* bih_tem = (const float*)d_in[15];
    const float* bhh_tem = (const float*)d_in[16];
    const float* Wm_wh = (const float*)d_in[17];
    const float* bm_wh = (const float*)d_in[18];
    const float* Wm_wt = (const float*)d_in[21];
    const float* bm_wt = (const float*)d_in[22];
    const float* Wm_pr = (const float*)d_in[25];
    const float* bm_pr = (const float*)d_in[26];
    const float* Ws_pr = (const float*)d_in[27];
    const float* bs_pr = (const float*)d_in[28];

    char* base_p = (char*)d_ws;
    size_t off = 0;
    auto carve = [&](size_t bytes) -> char* {
        char* r = base_p + off;
        off += (bytes + 255) & ~(size_t)255;
        return r;
    };
    bf16*  tin      = (bf16*) carve((size_t)NN*TIN_LD*2);
    float* gates    = (float*)carve((size_t)NN*1024*4);
    bf16*  W_tem    = (bf16*) carve((size_t)1024*TIN_LD*2);
    bf16*  W_rel    = (bf16*) carve((size_t)1024*RIN_LD*2);
    bf16*  Wg_bf    = (bf16*) carve((size_t)100*G1_LD*2);
    float* zwb_all  = (float*)carve((size_t)KO*NN*3*4);
    float* h_r      = (float*)carve((size_t)NN*HIDD*4);
    // zero block: c_r, zw1, zwhat1 contiguous
    float* c_r      = (float*)carve((size_t)NN*HIDD*4);
    float* zw1      = (float*)carve((size_t)NN*3*4);
    float* zwhat1   = (float*)carve((size_t)NN*50*4);
    float* zw0      = (float*)carve((size_t)NN*3*4);
    float* zwhat0   = (float*)carve((size_t)NN*50*4);
    size_t fixed_bytes = off;

    int CH = 1;
    for (int cand : {8, 4, 2}) {
        size_t need = fixed_bytes
                    + (((size_t)cand*NN*G1_LD*2 + 255) & ~(size_t)255)
                    + (((size_t)cand*NN*RIN_LD*2 + 255) & ~(size_t)255);
        if (need <= ws_size) { CH = cand; break; }
    }
    bf16* g1 = nullptr; int g1ld;
    bf16* rin;
    if (CH > 1) {
        g1   = (bf16*)carve((size_t)CH*NN*G1_LD*2);
        rin  = (bf16*)carve((size_t)CH*NN*RIN_LD*2);
        g1ld = G1_LD;
    } else {
        rin  = (bf16*)carve((size_t)NN*RIN_LD*2);
        g1   = tin;          // glimpse1 -> tin cols 0..2500; Wg pad cols (2500..2560) are zero
        g1ld = TIN_LD;
    }

    float* out        = (float*)d_out;
    float* out_zwhat  = out;
    float* out_zwhere = out + (size_t)NN*KO*50;
    float* out_zpres  = out_zwhere + (size_t)NN*KO*3;
    float* out_htemp  = out_zpres + (size_t)NN*KO;

    // ---- preamble (carry-independent) ----
    {
        int nz = NN*(HIDD + 3 + 50);   // c_r, zw1, zwhat1
        zero_f32<<<(nz+255)/256, 256, 0, stream>>>(c_r, nz);
    }
    zero_rin_carry<<<(NN*309+255)/256, 256, 0, stream>>>(rin);
    repack_w<<<((1024*RIN_LD)+255)/256, 256, 0, stream>>>(Wih_rel, 462, Whh_rel, 256, W_rel, RIN_LD, 1024);
    repack_w<<<((1024*TIN_LD)+255)/256, 256, 0, stream>>>(Wih_tem, 2862, Whh_tem, 256, W_tem, TIN_LD, 1024);
    repack_w<<<((100*G1_LD)+255)/256, 256, 0, stream>>>(Wg, 2500, nullptr, 0, Wg_bf, G1_LD, 100);
    zwb_all_v2<<<KO*NN/4, 256, 0, stream>>>(hidden_last, z_where_last, W_loca, b_loca, zwb_all);

    for (int cbase = 0; cbase < KO; cbase += CH) {
        // glimpse1 + rin static fill (fused)
        glimpse_batch<<<CH*NN, 256, 0, stream>>>(img, zwb_all + (size_t)cbase*NN*3, g1, g1ld,
                                                 rin, z_where_last, z_what_last, hidden_last, cbase);
        // enc GEMM: 1D swizzled grid, nxb=2
        mfma_gemm<1,1><<<2*CH*32, 256, 0, stream>>>(g1, g1ld, G1_LD, Wg_bf, G1_LD, 100, bg, nullptr, rin, RIN_LD, 2);

        for (int s = 0; s < CH; ++s) {
            int k = cbase + s;
            bf16* rin_k  = rin + (size_t)s*NN*RIN_LD;
            bf16* rin_nx = rin + (size_t)((s+1)%CH)*NN*RIN_LD;
            float* zw_cur     = (k & 1) ? zw1 : zw0;
            float* zw_prev    = (k & 1) ? zw0 : zw1;
            float* zwhat_cur  = (k & 1) ? zwhat1 : zwhat0;
            float* zwhat_prev = (k & 1) ? zwhat0 : zwhat1;

            // rel LSTM gates (ih+hh fused, K=768), 512 blocks, nxb=16
            mfma_gemm<0,0><<<512, 256, 0, stream>>>(rin_k, RIN_LD, RIN_LD, W_rel, RIN_LD, 1024, bih_rel, bhh_rel, gates, 1024, 16);
            // rel LSTM elementwise + zw + glimpse2 + tin fill (merged)
            rel_glimpse2<<<NN, 256, 0, stream>>>(gates, h_r, c_r, z_where_last, Wm_wh, bm_wh,
                                                 zw_cur, out_zwhere, rin_nx, tin,
                                                 img, zw_prev, zwhat_prev, z_what_last, hidden_last, k);
            // tem LSTM gates (ih+hh fused, K=3136), 512 blocks, nxb=16
            mfma_gemm<0,0><<<512, 256, 0, stream>>>(tin, TIN_LD, TIN_LD, W_tem, TIN_LD, 1024, bih_tem, bhh_tem, gates, 1024, 16);
            tem_fused<<<NN, 256, 0, stream>>>(gates, c_r, h_r, z_what_last, Wm_wt, bm_wt, Wm_pr, bm_pr, Ws_pr, bs_pr,
                                              zw_cur, z_pres_last, zwhat_cur, out_zwhat, out_htemp, out_zpres, rin_nx, k);
        }
    }
}

// Round 3
// 1198.366 us; speedup vs baseline: 1.1082x; 1.1082x over previous
//
#include <hip/hip_runtime.h>
#include <hip/hip_bf16.h>
#include <math.h>

typedef __attribute__((ext_vector_type(8))) short bf16x8;
typedef __attribute__((ext_vector_type(4))) float f32x4;
using bf16 = __hip_bfloat16;

constexpr int NN   = 2048;
constexpr int KO   = 8;
constexpr int IH   = 128, IW = 128;
constexpr int GS   = 50;
constexpr int HIDD = 256;
// rin: [enc 0..100 | zwl 100..103 | pzw 103..106 | zwhatl 106..156 | pzwhat 156..206 | hl 206..462 | h_r 462..718 | pad..768]
constexpr int RIN_LD = 768;
// tin: [g2 0..2500 | zw 2500..2503 | pzw 2503..2506 | zwhatl 2506..2556 | pzwhat 2556..2606 | hl 2606..2862 | h_r2 2862..3118 | pad..3136]
constexpr int TIN_LD = 3136;
constexpr int G1_LD  = 2560;
constexpr int GROWS  = 64;        // LDS-staged image rows for glimpse1 (32 KB)
constexpr int GROWS2 = 48;        // LDS-staged image rows for glimpse2 (24 KB)

__device__ __forceinline__ float sigm(float x) { return 1.f/(1.f+expf(-x)); }

// ===== MFMA GEMM v4: 64x64 tile, BK=64, global_load_lds dbuf (T3-minimum 2-phase),
// ===== XOR-swizzled LDS (pre-swizzled source, rule #21), optional split-K via grid.y.
template<int OUT_BF16, int RELU>
__global__ __launch_bounds__(256, 4) void mfma_gemm(
    const bf16* __restrict__ A, int lda, int Ktot,
    const bf16* __restrict__ Wt, int ldw, int M,
    const float* __restrict__ b1, const float* __restrict__ b2,
    void* __restrict__ Cout, int ldc, int nxb, int Kseg, int sstride)
{
    __shared__ __align__(16) bf16 As[2*4096];
    __shared__ __align__(16) bf16 Bs[2*4096];
    const int b    = blockIdx.x;
    const int xcd  = b & 7;
    const int t    = b >> 3;
    const int n0   = (xcd + 8*(t / nxb))*64;
    const int m0   = (t % nxb)*64;
    const int tid  = threadIdx.x;
    const int w    = tid>>6, lane = tid&63;
    const int wy   = w>>1, wx = w&1;
    const int q    = lane>>4, fr = lane&15;

    const int kbeg = blockIdx.y * Kseg;
    const int kend = min(Ktot, kbeg + Kseg);
    const int nk   = (kend - kbeg) >> 6;

    // staging source addresses: thread t stages 16B for (row r0 = t>>3 [+32 on round 1],
    // swizzled col csrc) -> linear LDS elem t*8 (+2048 on round 1).
    const int r0   = tid>>3;
    const int csrc = ((tid&7)*8) ^ ((r0&7)<<3);
    const bf16* pa = A + (size_t)(n0 + r0)*lda + kbeg + csrc;
    int wmr0 = m0 + r0;       if (wmr0 > M-1) wmr0 = M-1;
    int wmr1 = m0 + r0 + 32;  if (wmr1 > M-1) wmr1 = M-1;
    const bf16* pb  = Wt + (size_t)wmr0*ldw + kbeg + csrc;
    const bf16* pb1 = Wt + (size_t)wmr1*ldw + kbeg + csrc;

    f32x4 acc[2][2] = {};

    auto stage = [&](int buf, int koff) {
        bf16* la = As + buf*4096 + w*512;
        bf16* lb = Bs + buf*4096 + w*512;
        __builtin_amdgcn_global_load_lds(
            (const __attribute__((address_space(1))) void*)(pa + koff),
            (__attribute__((address_space(3))) void*)la, 16, 0, 0);
        __builtin_amdgcn_global_load_lds(
            (const __attribute__((address_space(1))) void*)(pa + koff + 32*(size_t)lda),
            (__attribute__((address_space(3))) void*)(la + 2048), 16, 0, 0);
        __builtin_amdgcn_global_load_lds(
            (const __attribute__((address_space(1))) void*)(pb + koff),
            (__attribute__((address_space(3))) void*)lb, 16, 0, 0);
        __builtin_amdgcn_global_load_lds(
            (const __attribute__((address_space(1))) void*)(pb1 + koff),
            (__attribute__((address_space(3))) void*)(lb + 2048), 16, 0, 0);
    };

    stage(0, 0);
    __syncthreads();           // drains vmcnt(0) -> buf0 staged for all waves
    int cur = 0;
    for (int kt = 0; kt < nk; ++kt) {
        if (kt + 1 < nk) stage(cur ^ 1, (kt + 1) << 6);   // issue-early: hides under compute
        const bf16* Ab = As + cur*4096;
        const bf16* Bb = Bs + cur*4096;
        bf16x8 av[2][2], bv[2][2];
        #pragma unroll
        for (int i=0;i<2;i++) {
            int r = wy*32 + i*16 + fr;
            int sw = (r&7)<<3, base = r*64;
            av[i][0] = *(const bf16x8*)(Ab + base + ((q*8) ^ sw));
            av[i][1] = *(const bf16x8*)(Ab + base + ((32 + q*8) ^ sw));
        }
        #pragma unroll
        for (int j=0;j<2;j++) {
            int r = wx*32 + j*16 + fr;
            int sw = (r&7)<<3, base = r*64;
            bv[j][0] = *(const bf16x8*)(Bb + base + ((q*8) ^ sw));
            bv[j][1] = *(const bf16x8*)(Bb + base + ((32 + q*8) ^ sw));
        }
        #pragma unroll
        for (int h=0;h<2;h++)
            #pragma unroll
            for (int i=0;i<2;i++)
                #pragma unroll
                for (int j=0;j<2;j++)
                    acc[i][j] = __builtin_amdgcn_mfma_f32_16x16x32_bf16(av[i][h], bv[j][h], acc[i][j], 0, 0, 0);
        __syncthreads();       // drain next-tile stage + protect buf reuse
        cur ^= 1;
    }

    #pragma unroll
    for (int j=0;j<2;j++) {
        int col = m0 + wx*32 + j*16 + fr;
        if (col < M) {
            float bias = 0.f;
            if (blockIdx.y == 0) {
                if (b1) bias += b1[col];
                if (b2) bias += b2[col];
            }
            #pragma unroll
            for (int i=0;i<2;i++) {
                #pragma unroll
                for (int reg=0;reg<4;reg++) {
                    float v = acc[i][j][reg] + bias;
                    if (RELU) v = fmaxf(v, 0.f);
                    size_t idx = (size_t)(n0 + wy*32 + i*16 + q*4 + reg)*ldc + col;
                    if (OUT_BF16) ((bf16*)Cout)[idx] = __float2bfloat16(v);
                    else          ((float*)Cout)[(size_t)blockIdx.y*sstride + idx] = v;
                }
            }
        }
    }
}

// ================= glimpse point math (global-gather path) =================
__device__ __forceinline__ void glimpse_points_global(const float* __restrict__ im,
                                                      float s, float tx, float ty,
                                                      bf16* __restrict__ drow) {
    const float GXS = 2.0f/49.0f;
    const float txp = tx + 1.0f, typ = ty + 1.0f;
    for (int p2 = threadIdx.x; p2 < 1250; p2 += 256) {
        int i = p2 / 25, j = (p2 - i*25)*2;
        float gy  = fmaf((float)i, GXS, -1.0f);
        float py  = fmaf(s, gy, typ)*63.5f;
        float y0f = floorf(py); float fy = py - y0f; int y0 = (int)y0f;
        float wy0 = ((unsigned)y0     < 128u) ? (1.f - fy) : 0.f;
        float wy1 = ((unsigned)(y0+1) < 128u) ? fy         : 0.f;
        const float* r0 = im + min(max(y0,  0),127)*IW;
        const float* r1 = im + min(max(y0+1,0),127)*IW;
        float gxa = fmaf((float)j, GXS, -1.0f);
        float pxa = fmaf(s, gxa, txp)*63.5f;
        float xa0f = floorf(pxa); float fa = pxa - xa0f; int xa0 = (int)xa0f;
        float wa0 = ((unsigned)xa0     < 128u) ? (1.f - fa) : 0.f;
        float wa1 = ((unsigned)(xa0+1) < 128u) ? fa         : 0.f;
        int xa0c = min(max(xa0,  0),127), xa1c = min(max(xa0+1,0),127);
        float gxb = fmaf((float)(j+1), GXS, -1.0f);
        float pxb = fmaf(s, gxb, txp)*63.5f;
        float xb0f = floorf(pxb); float fb = pxb - xb0f; int xb0 = (int)xb0f;
        float wb0 = ((unsigned)xb0     < 128u) ? (1.f - fb) : 0.f;
        float wb1 = ((unsigned)(xb0+1) < 128u) ? fb         : 0.f;
        int xb0c = min(max(xb0,  0),127), xb1c = min(max(xb0+1,0),127);

        float va = fmaf(wy1, fmaf(wa0, r1[xa0c], wa1*r1[xa1c]),
                   wy0 *     fmaf(wa0, r0[xa0c], wa1*r0[xa1c]));
        float vb = fmaf(wy1, fmaf(wb0, r1[xb0c], wb1*r1[xb1c]),
                   wy0 *     fmaf(wb0, r0[xb0c], wb1*r0[xb1c]));

        bf16 b0 = __float2bfloat16(va), b1 = __float2bfloat16(vb);
        unsigned short u0, u1;
        __builtin_memcpy(&u0, &b0, 2); __builtin_memcpy(&u1, &b1, 2);
        *(unsigned int*)(drow + i*GS + j) = (unsigned)u0 | ((unsigned)u1 << 16);
    }
}

// ================= glimpse point math (LDS row-staged path) =================
__device__ __forceinline__ void glimpse_points_lds(const float* __restrict__ rows,
                                                   int ylo, int nrows,
                                                   float s, float tx, float ty,
                                                   bf16* __restrict__ drow) {
    const float GXS = 2.0f/49.0f;
    const float txp = tx + 1.0f, typ = ty + 1.0f;
    for (int p2 = threadIdx.x; p2 < 1250; p2 += 256) {
        int i = p2 / 25, j = (p2 - i*25)*2;
        float gy  = fmaf((float)i, GXS, -1.0f);
        float py  = fmaf(s, gy, typ)*63.5f;
        float y0f = floorf(py); float fy = py - y0f; int y0 = (int)y0f;
        float wy0 = ((unsigned)y0     < 128u) ? (1.f - fy) : 0.f;
        float wy1 = ((unsigned)(y0+1) < 128u) ? fy         : 0.f;
        const float* r0 = rows + min(max(y0-ylo,   0), nrows-1)*IW;
        const float* r1 = rows + min(max(y0+1-ylo, 0), nrows-1)*IW;
        float gxa = fmaf((float)j, GXS, -1.0f);
        float pxa = fmaf(s, gxa, txp)*63.5f;
        float xa0f = floorf(pxa); float fa = pxa - xa0f; int xa0 = (int)xa0f;
        float wa0 = ((unsigned)xa0     < 128u) ? (1.f - fa) : 0.f;
        float wa1 = ((unsigned)(xa0+1) < 128u) ? fa         : 0.f;
        int xa0c = min(max(xa0,  0),127), xa1c = min(max(xa0+1,0),127);
        float gxb = fmaf((float)(j+1), GXS, -1.0f);
        float pxb = fmaf(s, gxb, txp)*63.5f;
        float xb0f = floorf(pxb); float fb = pxb - xb0f; int xb0 = (int)xb0f;
        float wb0 = ((unsigned)xb0     < 128u) ? (1.f - fb) : 0.f;
        float wb1 = ((unsigned)(xb0+1) < 128u) ? fb         : 0.f;
        int xb0c = min(max(xb0,  0),127), xb1c = min(max(xb0+1,0),127);
        float va = fmaf(wy1, fmaf(wa0, r1[xa0c], wa1*r1[xa1c]),
                   wy0 *     fmaf(wa0, r0[xa0c], wa1*r0[xa1c]));
        float vb = fmaf(wy1, fmaf(wb0, r1[xb0c], wb1*r1[xb1c]),
                   wy0 *     fmaf(wb0, r0[xb0c], wb1*r0[xb1c]));
        bf16 b0 = __float2bfloat16(va), b1 = __float2bfloat16(vb);
        unsigned short u0, u1;
        __builtin_memcpy(&u0, &b0, 2); __builtin_memcpy(&u1, &b1, 2);
        *(unsigned int*)(drow + i*GS + j) = (unsigned)u0 | ((unsigned)u1 << 16);
    }
}

// ========= glimpse1 (LDS row-staged, fallback global) + rin static-col fill, fused =========
__global__ __launch_bounds__(256) void glimpse_batch(const float* __restrict__ img,
                                                     const float* __restrict__ z,
                                                     bf16* __restrict__ dst, int ldd,
                                                     bf16* __restrict__ rin,
                                                     const float* __restrict__ z_where_last,
                                                     const float* __restrict__ z_what_last,
                                                     const float* __restrict__ hidden_last,
                                                     int cbase) {
    __shared__ float rows[GROWS*IW];
    int b = blockIdx.x;
    int n = b & (NN-1);
    int sl = b >> 11;
    const float* im = img + (size_t)n*IH*IW;
    float s  = z[b*3+0];
    float tx = z[b*3+1];
    float ty = z[b*3+2];
    bf16* drow = dst + (size_t)b*ldd;

    const float typ = ty + 1.0f;
    float pyA = fmaf(s, -1.f, typ)*63.5f;
    float pyB = fmaf(s,  1.f, typ)*63.5f;
    int ylo = (int)floorf(fminf(pyA, pyB));
    int yhi = (int)floorf(fmaxf(pyA, pyB)) + 1;
    ylo = min(max(ylo, 0), 127);
    yhi = min(max(yhi, 0), 127);
    int nrows = yhi - ylo + 1;

    if (nrows <= GROWS) {
        const float4* src = (const float4*)(im + ylo*IW);
        float4* d4 = (float4*)rows;
        int tot = nrows*(IW/4);
        for (int t = threadIdx.x; t < tot; t += 256) d4[t] = src[t];
        __syncthreads();
        glimpse_points_lds(rows, ylo, nrows, s, tx, ty, drow);
    } else {
        glimpse_points_global(im, s, tx, ty, drow);
    }

    // fused rin static-col fill: zwl(100..103), zwhatl(106..156), hl(206..462)
    int k = cbase + sl;
    bf16* rrow = rin + (size_t)b*RIN_LD;
    for (int c = threadIdx.x; c < 309; c += 256) {
        float v; int col;
        if (c < 3)       { col = 100 + c;      v = z_where_last[((size_t)n*KO + k)*3 + c]; }
        else if (c < 53) { col = 106 + (c-3);  v = z_what_last[((size_t)n*KO + k)*50 + (c-3)]; }
        else             { col = 206 + (c-53); v = hidden_last[((size_t)n*KO + k)*HIDD + (c-53)]; }
        rrow[col] = __float2bfloat16(v);
    }
}

// ===== merged per-step kernel: rel LSTM elementwise + zw linear + glimpse2 + tin fill =====
__global__ __launch_bounds__(256) void rel_glimpse2(
    const float* __restrict__ gates, const float* __restrict__ gates2,
    float* __restrict__ h_r, float* __restrict__ c_r,
    const float* __restrict__ z_where_last,
    const float* __restrict__ Wm_wh, const float* __restrict__ bm_wh,
    float* __restrict__ zw_cur, float* __restrict__ out_zwhere,
    bf16* __restrict__ rin_next, bf16* __restrict__ tin,
    const float* __restrict__ img,
    const float* __restrict__ zw_prev, const float* __restrict__ zwhat_prev,
    const float* __restrict__ z_what_last, const float* __restrict__ hidden_last, int k)
{
    __shared__ float rows[GROWS2*IW];
    __shared__ float hs[256];
    __shared__ float zws[3];
    int n = blockIdx.x, j = threadIdx.x;
    const float* g  = gates  + (size_t)n*1024;
    const float* g2 = gates2 + (size_t)n*1024;
    float ig = sigm(g[j]       + g2[j]);
    float fg = sigm(g[256+j]   + g2[256+j]);
    float gg = tanhf(g[512+j]  + g2[512+j]);
    float og = sigm(g[768+j]   + g2[768+j]);
    int cidx = n*256 + j;
    float c2 = fg*c_r[cidx] + ig*gg;
    float hv = og*tanhf(c2);
    c_r[cidx] = c2;
    h_r[cidx] = hv;
    hs[j] = hv;
    bf16 hb = __float2bfloat16(hv);
    rin_next[(size_t)n*RIN_LD + 462 + j] = hb;
    bf16* trow = tin + (size_t)n*TIN_LD;
    trow[2862 + j] = hb;
    __syncthreads();
    int w = j >> 6, lane = j & 63;
    if (w < 3) {
        const float* wt = Wm_wh + w*259;
        float sa = 0.f;
        for (int i = lane; i < 256; i += 64) sa = fmaf(hs[i], wt[3+i], sa);
        #pragma unroll
        for (int off = 32; off; off >>= 1) sa += __shfl_down(sa, off);
        if (lane == 0) {
            const float* zwl = z_where_last + ((size_t)n*KO + k)*3;
            float acc = bm_wh[w] + sa;
            for (int i = 0; i < 3; i++) acc = fmaf(zwl[i], wt[i], acc);
            zws[w] = acc;
            zw_cur[n*3+w] = acc;
            out_zwhere[((size_t)n*KO + k)*3 + w] = acc;
            bf16 ab = __float2bfloat16(acc);
            rin_next[(size_t)n*RIN_LD + 103 + w] = ab;
            trow[2500 + w] = ab;
        }
    }
    __syncthreads();
    float s = zws[0], tx = zws[1], ty = zws[2];
    const float* im = img + (size_t)n*IH*IW;
    {
        const float typ = ty + 1.0f;
        float pyA = fmaf(s, -1.f, typ)*63.5f;
        float pyB = fmaf(s,  1.f, typ)*63.5f;
        int ylo = (int)floorf(fminf(pyA, pyB));
        int yhi = (int)floorf(fmaxf(pyA, pyB)) + 1;
        ylo = min(max(ylo, 0), 127);
        yhi = min(max(yhi, 0), 127);
        int nrows = yhi - ylo + 1;
        if (nrows <= GROWS2) {
            const float4* src = (const float4*)(im + ylo*IW);
            float4* d4 = (float4*)rows;
            int tot = nrows*(IW/4);
            for (int t = threadIdx.x; t < tot; t += 256) d4[t] = src[t];
            __syncthreads();
            glimpse_points_lds(rows, ylo, nrows, s, tx, ty, trow);
        } else {
            glimpse_points_global(im, s, tx, ty, trow);
        }
    }
    for (int c = 3 + j; c < 362; c += 256) {
        float v;
        if      (c <   6) v = zw_prev[n*3 + c-3];
        else if (c <  56) v = z_what_last[((size_t)n*KO + k)*50 + c-6];
        else if (c < 106) v = zwhat_prev[n*50 + c-56];
        else              v = hidden_last[((size_t)n*KO + k)*HIDD + c-106];
        trow[2500 + c] = __float2bfloat16(v);
    }
}

// ================= small / preamble kernels =================
__global__ void zero_f32(float* __restrict__ p, int n) {
    int i = blockIdx.x*blockDim.x + threadIdx.x;
    if (i < n) p[i] = 0.f;
}

__global__ void repack_w(const float* __restrict__ s1, int K1,
                         const float* __restrict__ s2, int K2,
                         bf16* __restrict__ dst, int ldd, int M) {
    int gid = blockIdx.x*blockDim.x + threadIdx.x;
    if (gid >= M*ldd) return;
    int m = gid / ldd, c = gid - m*ldd;
    float v = 0.f;
    if (c < K1)           v = s1[(size_t)m*K1 + c];
    else if (c < K1+K2)   v = s2[(size_t)m*K2 + (c-K1)];
    dst[gid] = __float2bfloat16(v);
}

__global__ __launch_bounds__(256) void zwb_all_v2(const float* __restrict__ hidden_last,
                                                  const float* __restrict__ z_where_last,
                                                  const float* __restrict__ Wl, const float* __restrict__ bl,
                                                  float* __restrict__ zwb_all) {
    __shared__ float wls[768];
    for (int i = threadIdx.x; i < 768; i += 256) wls[i] = Wl[i];
    __syncthreads();
    int wv = threadIdx.x>>6, lane = threadIdx.x&63;
    int row = blockIdx.x*4 + wv;
    int s = row >> 11, n = row & (NN-1);
    const float* hl = hidden_last + ((size_t)n*KO + s)*HIDD;
    float4 h4 = *(const float4*)(hl + lane*4);
    float s0=0.f, s1=0.f, s2=0.f;
    #pragma unroll
    for (int r4=0;r4<4;r4++) {
        float hv = ((const float*)&h4)[r4];
        int i = lane*4 + r4;
        s0 = fmaf(hv, wls[i],     s0);
        s1 = fmaf(hv, wls[256+i], s1);
        s2 = fmaf(hv, wls[512+i], s2);
    }
    #pragma unroll
    for (int off=32; off; off>>=1) {
        s0 += __shfl_down(s0,off); s1 += __shfl_down(s1,off); s2 += __shfl_down(s2,off);
    }
    if (lane == 0) {
        const float* zwl = z_where_last + ((size_t)n*KO + s)*3;
        zwb_all[row*3+0] = fmaxf(s0+bl[0],0.f) + zwl[0];
        zwb_all[row*3+1] = fmaxf(s1+bl[1],0.f) + zwl[1];
        zwb_all[row*3+2] = fmaxf(s2+bl[2],0.f) + zwl[2];
    }
}

__global__ void zero_rin_carry(bf16* __restrict__ rin0) {
    int gid = blockIdx.x*blockDim.x + threadIdx.x;
    if (gid >= NN*309) return;
    int c = gid % 309, n = gid/309;
    int col = (c < 3) ? 103+c : ((c < 53) ? 156+(c-3) : 462+(c-53));
    rin0[(size_t)n*RIN_LD + col] = __float2bfloat16(0.f);
}

// ================= tem LSTM + zwhat + pres (block per n) =================
__global__ __launch_bounds__(256) void tem_fused(
    const float* __restrict__ gates, const float* __restrict__ gates2,
    const float* __restrict__ c_r, const float* __restrict__ h_r,
    const float* __restrict__ z_what_last,
    const float* __restrict__ Wm_wt, const float* __restrict__ bm_wt,
    const float* __restrict__ Wm_pr, const float* __restrict__ bm_pr,
    const float* __restrict__ Ws_pr, const float* __restrict__ bs_pr,
    const float* __restrict__ zw_cur, const float* __restrict__ z_pres_last,
    float* __restrict__ zwhat_cur, float* __restrict__ out_zwhat,
    float* __restrict__ out_htemp, float* __restrict__ out_zpres,
    bf16* __restrict__ rin_next, int k)
{
    __shared__ float L[615];
    int n = blockIdx.x, j = threadIdx.x;
    const float* g  = gates  + (size_t)n*1024;
    const float* g2 = gates2 + (size_t)n*1024;
    float ig = sigm(g[j]       + g2[j]);
    float fg = sigm(g[256+j]   + g2[256+j]);
    float gg = tanhf(g[512+j]  + g2[512+j]);
    float og = sigm(g[768+j]   + g2[768+j]);
    float c2 = fg*c_r[n*256+j] + ig*gg;
    float hv = og*tanhf(c2);
    out_htemp[((size_t)n*KO + k)*HIDD + j] = hv;
    L[309+j] = hv;
    L[53+j]  = h_r[n*256+j];
    if (j < 50)      L[j]  = z_what_last[((size_t)n*KO + k)*50 + j];
    else if (j < 53) L[j]  = zw_cur[n*3 + (j-50)];
    __syncthreads();
    if (j < 200) {
        int m = j >> 2, part = j & 3;
        const float* wt = Wm_wt + m*562;
        float s = 0.f;
        for (int i = part; i < 562; i += 4) {
            float v = (i < 50) ? L[i] : L[i+3];
            s = fmaf(v, wt[i], s);
        }
        s += __shfl_down(s, 2);
        s += __shfl_down(s, 1);
        if (part == 0) {
            float acc = s + bm_wt[m];
            zwhat_cur[n*50+m] = acc;
            out_zwhat[((size_t)n*KO + k)*50 + m] = acc;
            rin_next[(size_t)n*RIN_LD + 156 + m] = __float2bfloat16(acc);
            L[565+m] = acc;
        }
    }
    __syncthreads();
    if (j < 64) {
        float s1 = 0.f, s2 = 0.f;
        for (int i = j; i < 565; i += 64) {
            float v = (i < 50) ? L[565+i] : L[i];
            s1 = fmaf(v, Wm_pr[i], s1);
            s2 = fmaf(v, Ws_pr[i], s2);
        }
        #pragma unroll
        for (int off = 32; off; off >>= 1) { s1 += __shfl_down(s1,off); s2 += __shfl_down(s2,off); }
        if (j == 0) {
            float p = sigm(s1 + bm_pr[0]) * sigm(s2 + bs_pr[0]);
            out_zpres[(size_t)n*KO + k] = p * z_pres_last[(size_t)n*KO + k];
        }
    }
}

extern "C" void kernel_launch(void* const* d_in, const int* in_sizes, int n_in,
                              void* d_out, int out_size, void* d_ws, size_t ws_size,
                              hipStream_t stream) {
    (void)in_sizes; (void)n_in; (void)out_size;
    const float* img          = (const float*)d_in[0];
    const float* z_what_last  = (const float*)d_in[1];
    const float* z_where_last = (const float*)d_in[2];
    const float* z_pres_last  = (const float*)d_in[3];
    const float* hidden_last  = (const float*)d_in[4];
    const float* W_loca = (const float*)d_in[5];
    const float* b_loca = (const float*)d_in[6];
    const float* Wg     = (const float*)d_in[7];
    const float* bg     = (const float*)d_in[8];
    const float* Wih_rel = (const float*)d_in[9];
    const float* Whh_rel = (const float*)d_in[10];
    const float* bih_rel = (const float*)d_in[11];
    const float* bhh_rel = (const float*)d_in[12];
    const float* Wih_tem = (const float*)d_in[13];
    const float* Whh_tem = (const float*)d_in[14];
    const float* bih_tem = (const float*)d_in[15];
    const float* bhh_tem = (const float*)d_in[16];
    const float* Wm_wh = (const float*)d_in[17];
    const float* bm_wh = (const float*)d_in[18];
    const float* Wm_wt = (const float*)d_in[21];
    const float* bm_wt = (const float*)d_in[22];
    const float* Wm_pr = (const float*)d_in[25];
    const float* bm_pr = (const float*)d_in[26];
    const float* Ws_pr = (const float*)d_in[27];
    const float* bs_pr = (const float*)d_in[28];

    char* base_p = (char*)d_ws;
    size_t off = 0;
    auto carve = [&](size_t bytes) -> char* {
        char* r = base_p + off;
        off += (bytes + 255) & ~(size_t)255;
        return r;
    };
    bf16*  tin      = (bf16*) carve((size_t)NN*TIN_LD*2);
    float* gates    = (float*)carve((size_t)2*NN*1024*4);   // 2 split-K halves
    bf16*  W_tem    = (bf16*) carve((size_t)1024*TIN_LD*2);
    bf16*  W_rel    = (bf16*) carve((size_t)1024*RIN_LD*2);
    bf16*  Wg_bf    = (bf16*) carve((size_t)100*G1_LD*2);
    float* zwb_all  = (float*)carve((size_t)KO*NN*3*4);
    float* h_r      = (float*)carve((size_t)NN*HIDD*4);
    // zero block: c_r, zw1, zwhat1 contiguous
    float* c_r      = (float*)carve((size_t)NN*HIDD*4);
    float* zw1      = (float*)carve((size_t)NN*3*4);
    float* zwhat1   = (float*)carve((size_t)NN*50*4);
    float* zw0      = (float*)carve((size_t)NN*3*4);
    float* zwhat0   = (float*)carve((size_t)NN*50*4);
    size_t fixed_bytes = off;
    float* gates2 = gates + (size_t)NN*1024;

    int CH = 1;
    for (int cand : {8, 4, 2}) {
        size_t need = fixed_bytes
                    + (((size_t)cand*NN*G1_LD*2 + 255) & ~(size_t)255)
                    + (((size_t)cand*NN*RIN_LD*2 + 255) & ~(size_t)255);
        if (need <= ws_size) { CH = cand; break; }
    }
    bf16* g1 = nullptr; int g1ld;
    bf16* rin;
    if (CH > 1) {
        g1   = (bf16*)carve((size_t)CH*NN*G1_LD*2);
        rin  = (bf16*)carve((size_t)CH*NN*RIN_LD*2);
        g1ld = G1_LD;
    } else {
        rin  = (bf16*)carve((size_t)NN*RIN_LD*2);
        g1   = tin;          // glimpse1 -> tin cols 0..2500; Wg pad cols (2500..2560) are zero
        g1ld = TIN_LD;
    }

    float* out        = (float*)d_out;
    float* out_zwhat  = out;
    float* out_zwhere = out + (size_t)NN*KO*50;
    float* out_zpres  = out_zwhere + (size_t)NN*KO*3;
    float* out_htemp  = out_zpres + (size_t)NN*KO;

    // ---- preamble (carry-independent) ----
    {
        int nz = NN*(HIDD + 3 + 50);   // c_r, zw1, zwhat1
        zero_f32<<<(nz+255)/256, 256, 0, stream>>>(c_r, nz);
    }
    zero_rin_carry<<<(NN*309+255)/256, 256, 0, stream>>>(rin);
    repack_w<<<((1024*RIN_LD)+255)/256, 256, 0, stream>>>(Wih_rel, 462, Whh_rel, 256, W_rel, RIN_LD, 1024);
    repack_w<<<((1024*TIN_LD)+255)/256, 256, 0, stream>>>(Wih_tem, 2862, Whh_tem, 256, W_tem, TIN_LD, 1024);
    repack_w<<<((100*G1_LD)+255)/256, 256, 0, stream>>>(Wg, 2500, nullptr, 0, Wg_bf, G1_LD, 100);
    zwb_all_v2<<<KO*NN/4, 256, 0, stream>>>(hidden_last, z_where_last, W_loca, b_loca, zwb_all);

    const int GSTR = NN*1024;           // split-K output stride (floats)
    const int KSEG_REL = 384;           // 768/2
    const int KSEG_TEM = 1600;          // ceil(49/2)*64

    for (int cbase = 0; cbase < KO; cbase += CH) {
        // glimpse1 + rin static fill (fused)
        glimpse_batch<<<CH*NN, 256, 0, stream>>>(img, zwb_all + (size_t)cbase*NN*3, g1, g1ld,
                                                 rin, z_where_last, z_what_last, hidden_last, cbase);
        // enc GEMM: 1D swizzled grid, nxb=2, no split
        mfma_gemm<1,1><<<dim3(2*CH*32,1), 256, 0, stream>>>(g1, g1ld, G1_LD, Wg_bf, G1_LD, 100,
                                                            bg, nullptr, rin, RIN_LD, 2, G1_LD, 0);

        for (int s = 0; s < CH; ++s) {
            int k = cbase + s;
            bf16* rin_k  = rin + (size_t)s*NN*RIN_LD;
            bf16* rin_nx = rin + (size_t)((s+1)%CH)*NN*RIN_LD;
            float* zw_cur     = (k & 1) ? zw1 : zw0;
            float* zw_prev    = (k & 1) ? zw0 : zw1;
            float* zwhat_cur  = (k & 1) ? zwhat1 : zwhat0;
            float* zwhat_prev = (k & 1) ? zwhat0 : zwhat1;

            // rel LSTM gates (ih+hh fused, K=768), split-K=2 -> 1024 blocks, 4/CU
            mfma_gemm<0,0><<<dim3(512,2), 256, 0, stream>>>(rin_k, RIN_LD, RIN_LD, W_rel, RIN_LD, 1024,
                                                            bih_rel, bhh_rel, gates, 1024, 16, KSEG_REL, GSTR);
            rel_glimpse2<<<NN, 256, 0, stream>>>(gates, gates2, h_r, c_r, z_where_last, Wm_wh, bm_wh,
                                                 zw_cur, out_zwhere, rin_nx, tin,
                                                 img, zw_prev, zwhat_prev, z_what_last, hidden_last, k);
            // tem LSTM gates (ih+hh fused, K=3136), split-K=2 -> 1024 blocks, 4/CU
            mfma_gemm<0,0><<<dim3(512,2), 256, 0, stream>>>(tin, TIN_LD, TIN_LD, W_tem, TIN_LD, 1024,
                                                            bih_tem, bhh_tem, gates, 1024, 16, KSEG_TEM, GSTR);
            tem_fused<<<NN, 256, 0, stream>>>(gates, gates2, c_r, h_r, z_what_last, Wm_wt, bm_wt, Wm_pr, bm_pr, Ws_pr, bs_pr,
                                              zw_cur, z_pres_last, zwhat_cur, out_zwhat, out_htemp, out_zpres, rin_nx, k);
        }
    }
}

// Round 4
// 1138.427 us; speedup vs baseline: 1.1665x; 1.0527x over previous
//
#include <hip/hip_runtime.h>
#include <hip/hip_bf16.h>
#include <math.h>

typedef __attribute__((ext_vector_type(8))) short bf16x8;
typedef __attribute__((ext_vector_type(4))) float f32x4;
using bf16 = __hip_bfloat16;

constexpr int NN   = 2048;
constexpr int KO   = 8;
constexpr int IH   = 128, IW = 128;
constexpr int GS   = 50;
constexpr int HIDD = 256;
// rin: [enc 0..100 | zwl 100..103 | pzw 103..106 | zwhatl 106..156 | pzwhat 156..206 | hl 206..462 | h_r 462..718 | pad..768]
constexpr int RIN_LD = 768;
// tin: [g2 0..2500 | zw 2500..2503 | pzw 2503..2506 | zwhatl 2506..2556 | pzwhat 2556..2606 | hl 2606..2862 | h_r2 2862..3118 | pad..3136]
constexpr int TIN_LD = 3136;
constexpr int G1_LD  = 2560;

__device__ __forceinline__ float sigm(float x) { return 1.f/(1.f+expf(-x)); }

// ===== MFMA GEMM v4: 64x64 tile, BK=64, global_load_lds dbuf (T3-minimum 2-phase),
// ===== XOR-swizzled LDS (pre-swizzled source, rule #21), optional split-K via grid.y.
template<int OUT_BF16, int RELU>
__global__ __launch_bounds__(256, 4) void mfma_gemm(
    const bf16* __restrict__ A, int lda, int Ktot,
    const bf16* __restrict__ Wt, int ldw, int M,
    const float* __restrict__ b1, const float* __restrict__ b2,
    void* __restrict__ Cout, int ldc, int nxb, int Kseg, int sstride)
{
    __shared__ __align__(16) bf16 As[2*4096];
    __shared__ __align__(16) bf16 Bs[2*4096];
    const int b    = blockIdx.x;
    const int xcd  = b & 7;
    const int t    = b >> 3;
    const int n0   = (xcd + 8*(t / nxb))*64;
    const int m0   = (t % nxb)*64;
    const int tid  = threadIdx.x;
    const int w    = tid>>6, lane = tid&63;
    const int wy   = w>>1, wx = w&1;
    const int q    = lane>>4, fr = lane&15;

    const int kbeg = blockIdx.y * Kseg;
    const int kend = min(Ktot, kbeg + Kseg);
    const int nk   = (kend - kbeg) >> 6;

    const int r0   = tid>>3;
    const int csrc = ((tid&7)*8) ^ ((r0&7)<<3);
    const bf16* pa = A + (size_t)(n0 + r0)*lda + kbeg + csrc;
    int wmr0 = m0 + r0;       if (wmr0 > M-1) wmr0 = M-1;
    int wmr1 = m0 + r0 + 32;  if (wmr1 > M-1) wmr1 = M-1;
    const bf16* pb  = Wt + (size_t)wmr0*ldw + kbeg + csrc;
    const bf16* pb1 = Wt + (size_t)wmr1*ldw + kbeg + csrc;

    f32x4 acc[2][2] = {};

    auto stage = [&](int buf, int koff) {
        bf16* la = As + buf*4096 + w*512;
        bf16* lb = Bs + buf*4096 + w*512;
        __builtin_amdgcn_global_load_lds(
            (const __attribute__((address_space(1))) void*)(pa + koff),
            (__attribute__((address_space(3))) void*)la, 16, 0, 0);
        __builtin_amdgcn_global_load_lds(
            (const __attribute__((address_space(1))) void*)(pa + koff + 32*(size_t)lda),
            (__attribute__((address_space(3))) void*)(la + 2048), 16, 0, 0);
        __builtin_amdgcn_global_load_lds(
            (const __attribute__((address_space(1))) void*)(pb + koff),
            (__attribute__((address_space(3))) void*)lb, 16, 0, 0);
        __builtin_amdgcn_global_load_lds(
            (const __attribute__((address_space(1))) void*)(pb1 + koff),
            (__attribute__((address_space(3))) void*)(lb + 2048), 16, 0, 0);
    };

    stage(0, 0);
    __syncthreads();
    int cur = 0;
    for (int kt = 0; kt < nk; ++kt) {
        if (kt + 1 < nk) stage(cur ^ 1, (kt + 1) << 6);
        const bf16* Ab = As + cur*4096;
        const bf16* Bb = Bs + cur*4096;
        bf16x8 av[2][2], bv[2][2];
        #pragma unroll
        for (int i=0;i<2;i++) {
            int r = wy*32 + i*16 + fr;
            int sw = (r&7)<<3, base = r*64;
            av[i][0] = *(const bf16x8*)(Ab + base + ((q*8) ^ sw));
            av[i][1] = *(const bf16x8*)(Ab + base + ((32 + q*8) ^ sw));
        }
        #pragma unroll
        for (int j=0;j<2;j++) {
            int r = wx*32 + j*16 + fr;
            int sw = (r&7)<<3, base = r*64;
            bv[j][0] = *(const bf16x8*)(Bb + base + ((q*8) ^ sw));
            bv[j][1] = *(const bf16x8*)(Bb + base + ((32 + q*8) ^ sw));
        }
        #pragma unroll
        for (int h=0;h<2;h++)
            #pragma unroll
            for (int i=0;i<2;i++)
                #pragma unroll
                for (int j=0;j<2;j++)
                    acc[i][j] = __builtin_amdgcn_mfma_f32_16x16x32_bf16(av[i][h], bv[j][h], acc[i][j], 0, 0, 0);
        __syncthreads();
        cur ^= 1;
    }

    #pragma unroll
    for (int j=0;j<2;j++) {
        int col = m0 + wx*32 + j*16 + fr;
        if (col < M) {
            float bias = 0.f;
            if (blockIdx.y == 0) {
                if (b1) bias += b1[col];
                if (b2) bias += b2[col];
            }
            #pragma unroll
            for (int i=0;i<2;i++) {
                #pragma unroll
                for (int reg=0;reg<4;reg++) {
                    float v = acc[i][j][reg] + bias;
                    if (RELU) v = fmaxf(v, 0.f);
                    size_t idx = (size_t)(n0 + wy*32 + i*16 + q*4 + reg)*ldc + col;
                    if (OUT_BF16) ((bf16*)Cout)[idx] = __float2bfloat16(v);
                    else          ((float*)Cout)[(size_t)blockIdx.y*sstride + idx] = v;
                }
            }
        }
    }
}

// ================= glimpse point math (global-gather path) =================
__device__ __forceinline__ void glimpse_points_global(const float* __restrict__ im,
                                                      float s, float tx, float ty,
                                                      bf16* __restrict__ drow) {
    const float GXS = 2.0f/49.0f;
    const float txp = tx + 1.0f, typ = ty + 1.0f;
    for (int p2 = threadIdx.x; p2 < 1250; p2 += 256) {
        int i = p2 / 25, j = (p2 - i*25)*2;
        float gy  = fmaf((float)i, GXS, -1.0f);
        float py  = fmaf(s, gy, typ)*63.5f;
        float y0f = floorf(py); float fy = py - y0f; int y0 = (int)y0f;
        float wy0 = ((unsigned)y0     < 128u) ? (1.f - fy) : 0.f;
        float wy1 = ((unsigned)(y0+1) < 128u) ? fy         : 0.f;
        const float* r0 = im + min(max(y0,  0),127)*IW;
        const float* r1 = im + min(max(y0+1,0),127)*IW;
        float gxa = fmaf((float)j, GXS, -1.0f);
        float pxa = fmaf(s, gxa, txp)*63.5f;
        float xa0f = floorf(pxa); float fa = pxa - xa0f; int xa0 = (int)xa0f;
        float wa0 = ((unsigned)xa0     < 128u) ? (1.f - fa) : 0.f;
        float wa1 = ((unsigned)(xa0+1) < 128u) ? fa         : 0.f;
        int xa0c = min(max(xa0,  0),127), xa1c = min(max(xa0+1,0),127);
        float gxb = fmaf((float)(j+1), GXS, -1.0f);
        float pxb = fmaf(s, gxb, txp)*63.5f;
        float xb0f = floorf(pxb); float fb = pxb - xb0f; int xb0 = (int)xb0f;
        float wb0 = ((unsigned)xb0     < 128u) ? (1.f - fb) : 0.f;
        float wb1 = ((unsigned)(xb0+1) < 128u) ? fb         : 0.f;
        int xb0c = min(max(xb0,  0),127), xb1c = min(max(xb0+1,0),127);

        float va = fmaf(wy1, fmaf(wa0, r1[xa0c], wa1*r1[xa1c]),
                   wy0 *     fmaf(wa0, r0[xa0c], wa1*r0[xa1c]));
        float vb = fmaf(wy1, fmaf(wb0, r1[xb0c], wb1*r1[xb1c]),
                   wy0 *     fmaf(wb0, r0[xb0c], wb1*r0[xb1c]));

        bf16 b0 = __float2bfloat16(va), b1 = __float2bfloat16(vb);
        unsigned short u0, u1;
        __builtin_memcpy(&u0, &b0, 2); __builtin_memcpy(&u1, &b1, 2);
        *(unsigned int*)(drow + i*GS + j) = (unsigned)u0 | ((unsigned)u1 << 16);
    }
}

// ===== per-point sampler from full-image LDS copy (identical math to global path) =====
__device__ __forceinline__ void sample_pair_lds(const float* __restrict__ im_s,
                                                float s, float txp, float typ,
                                                int i, int j, bf16* __restrict__ drow) {
    const float GXS = 2.0f/49.0f;
    float gy  = fmaf((float)i, GXS, -1.0f);
    float py  = fmaf(s, gy, typ)*63.5f;
    float y0f = floorf(py); float fy = py - y0f; int y0 = (int)y0f;
    float wy0 = ((unsigned)y0     < 128u) ? (1.f - fy) : 0.f;
    float wy1 = ((unsigned)(y0+1) < 128u) ? fy         : 0.f;
    const float* r0 = im_s + min(max(y0,  0),127)*IW;
    const float* r1 = im_s + min(max(y0+1,0),127)*IW;
    float gxa = fmaf((float)j, GXS, -1.0f);
    float pxa = fmaf(s, gxa, txp)*63.5f;
    float xa0f = floorf(pxa); float fa = pxa - xa0f; int xa0 = (int)xa0f;
    float wa0 = ((unsigned)xa0     < 128u) ? (1.f - fa) : 0.f;
    float wa1 = ((unsigned)(xa0+1) < 128u) ? fa         : 0.f;
    int xa0c = min(max(xa0,  0),127), xa1c = min(max(xa0+1,0),127);
    float gxb = fmaf((float)(j+1), GXS, -1.0f);
    float pxb = fmaf(s, gxb, txp)*63.5f;
    float xb0f = floorf(pxb); float fb = pxb - xb0f; int xb0 = (int)xb0f;
    float wb0 = ((unsigned)xb0     < 128u) ? (1.f - fb) : 0.f;
    float wb1 = ((unsigned)(xb0+1) < 128u) ? fb         : 0.f;
    int xb0c = min(max(xb0,  0),127), xb1c = min(max(xb0+1,0),127);
    float va = fmaf(wy1, fmaf(wa0, r1[xa0c], wa1*r1[xa1c]),
               wy0 *     fmaf(wa0, r0[xa0c], wa1*r0[xa1c]));
    float vb = fmaf(wy1, fmaf(wb0, r1[xb0c], wb1*r1[xb1c]),
               wy0 *     fmaf(wb0, r0[xb0c], wb1*r0[xb1c]));
    bf16 b0 = __float2bfloat16(va), b1 = __float2bfloat16(vb);
    unsigned short u0, u1;
    __builtin_memcpy(&u0, &b0, 2); __builtin_memcpy(&u1, &b1, 2);
    *(unsigned int*)(drow + i*GS + j) = (unsigned)u0 | ((unsigned)u1 << 16);
}

// ========= glimpse1 v2: one block per n; full image staged once in LDS (64 KB);
// ========= all CH slices' glimpses + rin static-col fills computed from it.
__global__ __launch_bounds__(512) void glimpse_all(const float* __restrict__ img,
                                                   const float* __restrict__ zwb,   // + cbase*NN*3
                                                   bf16* __restrict__ dst, int ldd,
                                                   bf16* __restrict__ rin,
                                                   const float* __restrict__ z_where_last,
                                                   const float* __restrict__ z_what_last,
                                                   const float* __restrict__ hidden_last,
                                                   int cbase, int CH) {
    __shared__ float im_s[IH*IW];          // 64 KB -> 2 blocks/CU
    const int n = blockIdx.x;
    const float* im = img + (size_t)n*IH*IW;
    {
        const float4* s4 = (const float4*)im;
        float4* d4 = (float4*)im_s;
        #pragma unroll
        for (int t = threadIdx.x; t < IH*IW/4; t += 512) d4[t] = s4[t];
    }
    __syncthreads();

    const int tot = CH*1250;
    for (int p = threadIdx.x; p < tot; p += 512) {
        int sl = p / 1250, p2 = p - sl*1250;
        int i = p2 / 25, j = (p2 - i*25)*2;
        const float* zr = zwb + (size_t)(sl*NN + n)*3;
        float s = zr[0], txp = zr[1] + 1.0f, typ = zr[2] + 1.0f;
        sample_pair_lds(im_s, s, txp, typ, i, j, dst + (size_t)(sl*NN + n)*ldd);
    }

    // rin static-col fill for all CH slices: zwl(100..103), zwhatl(106..156), hl(206..462)
    const int tot2 = CH*309;
    for (int t = threadIdx.x; t < tot2; t += 512) {
        int sl = t / 309, c = t - sl*309;
        int k = cbase + sl;
        bf16* rrow = rin + (size_t)(sl*NN + n)*RIN_LD;
        float v; int col;
        if (c < 3)       { col = 100 + c;      v = z_where_last[((size_t)n*KO + k)*3 + c]; }
        else if (c < 53) { col = 106 + (c-3);  v = z_what_last[((size_t)n*KO + k)*50 + (c-3)]; }
        else             { col = 206 + (c-53); v = hidden_last[((size_t)n*KO + k)*HIDD + (c-53)]; }
        rrow[col] = __float2bfloat16(v);
    }
}

// ===== merged per-step kernel: rel LSTM elementwise + zw linear + glimpse2 + tin fill =====
// glimpse2 uses the global-gather path (image is L3-resident; LDS staging proven neutral,
// and dropping it frees 24 KB LDS -> 8 blocks/CU).
__global__ __launch_bounds__(256) void rel_glimpse2(
    const float* __restrict__ gates, const float* __restrict__ gates2,
    float* __restrict__ h_r, float* __restrict__ c_r,
    const float* __restrict__ z_where_last,
    const float* __restrict__ Wm_wh, const float* __restrict__ bm_wh,
    float* __restrict__ zw_cur, float* __restrict__ out_zwhere,
    bf16* __restrict__ rin_next, bf16* __restrict__ tin,
    const float* __restrict__ img,
    const float* __restrict__ zw_prev, const float* __restrict__ zwhat_prev,
    const float* __restrict__ z_what_last, const float* __restrict__ hidden_last, int k)
{
    __shared__ float hs[256];
    __shared__ float zws[3];
    int n = blockIdx.x, j = threadIdx.x;
    const float* g  = gates  + (size_t)n*1024;
    const float* g2 = gates2 + (size_t)n*1024;
    float ig = sigm(g[j]       + g2[j]);
    float fg = sigm(g[256+j]   + g2[256+j]);
    float gg = tanhf(g[512+j]  + g2[512+j]);
    float og = sigm(g[768+j]   + g2[768+j]);
    int cidx = n*256 + j;
    float c2 = fg*c_r[cidx] + ig*gg;
    float hv = og*tanhf(c2);
    c_r[cidx] = c2;
    h_r[cidx] = hv;
    hs[j] = hv;
    bf16 hb = __float2bfloat16(hv);
    rin_next[(size_t)n*RIN_LD + 462 + j] = hb;
    bf16* trow = tin + (size_t)n*TIN_LD;
    trow[2862 + j] = hb;
    __syncthreads();
    int w = j >> 6, lane = j & 63;
    if (w < 3) {
        const float* wt = Wm_wh + w*259;
        float sa = 0.f;
        for (int i = lane; i < 256; i += 64) sa = fmaf(hs[i], wt[3+i], sa);
        #pragma unroll
        for (int off = 32; off; off >>= 1) sa += __shfl_down(sa, off);
        if (lane == 0) {
            const float* zwl = z_where_last + ((size_t)n*KO + k)*3;
            float acc = bm_wh[w] + sa;
            for (int i = 0; i < 3; i++) acc = fmaf(zwl[i], wt[i], acc);
            zws[w] = acc;
            zw_cur[n*3+w] = acc;
            out_zwhere[((size_t)n*KO + k)*3 + w] = acc;
            bf16 ab = __float2bfloat16(acc);
            rin_next[(size_t)n*RIN_LD + 103 + w] = ab;
            trow[2500 + w] = ab;
        }
    }
    __syncthreads();
    float s = zws[0], tx = zws[1], ty = zws[2];
    glimpse_points_global(img + (size_t)n*IH*IW, s, tx, ty, trow);
    for (int c = 3 + j; c < 362; c += 256) {
        float v;
        if      (c <   6) v = zw_prev[n*3 + c-3];
        else if (c <  56) v = z_what_last[((size_t)n*KO + k)*50 + c-6];
        else if (c < 106) v = zwhat_prev[n*50 + c-56];
        else              v = hidden_last[((size_t)n*KO + k)*HIDD + c-106];
        trow[2500 + c] = __float2bfloat16(v);
    }
}

// ================= small / preamble kernels =================
__global__ void zero_f32(float* __restrict__ p, int n) {
    int i = blockIdx.x*blockDim.x + threadIdx.x;
    if (i < n) p[i] = 0.f;
}

__global__ void repack_w(const float* __restrict__ s1, int K1,
                         const float* __restrict__ s2, int K2,
                         bf16* __restrict__ dst, int ldd, int M) {
    int gid = blockIdx.x*blockDim.x + threadIdx.x;
    if (gid >= M*ldd) return;
    int m = gid / ldd, c = gid - m*ldd;
    float v = 0.f;
    if (c < K1)           v = s1[(size_t)m*K1 + c];
    else if (c < K1+K2)   v = s2[(size_t)m*K2 + (c-K1)];
    dst[gid] = __float2bfloat16(v);
}

// transpose Wm_wt (50 x 562, f32) -> wt_t (576 x 64, f32, zero-padded)
__global__ void transpose_wmwt(const float* __restrict__ W, float* __restrict__ Wt) {
    int gid = blockIdx.x*blockDim.x + threadIdx.x;
    if (gid >= 576*64) return;
    int i = gid >> 6, m = gid & 63;
    Wt[gid] = (m < 50 && i < 562) ? W[(size_t)m*562 + i] : 0.f;
}

__global__ __launch_bounds__(256) void zwb_all_v2(const float* __restrict__ hidden_last,
                                                  const float* __restrict__ z_where_last,
                                                  const float* __restrict__ Wl, const float* __restrict__ bl,
                                                  float* __restrict__ zwb_all) {
    __shared__ float wls[768];
    for (int i = threadIdx.x; i < 768; i += 256) wls[i] = Wl[i];
    __syncthreads();
    int wv = threadIdx.x>>6, lane = threadIdx.x&63;
    int row = blockIdx.x*4 + wv;
    int s = row >> 11, n = row & (NN-1);
    const float* hl = hidden_last + ((size_t)n*KO + s)*HIDD;
    float4 h4 = *(const float4*)(hl + lane*4);
    float s0=0.f, s1=0.f, s2=0.f;
    #pragma unroll
    for (int r4=0;r4<4;r4++) {
        float hv = ((const float*)&h4)[r4];
        int i = lane*4 + r4;
        s0 = fmaf(hv, wls[i],     s0);
        s1 = fmaf(hv, wls[256+i], s1);
        s2 = fmaf(hv, wls[512+i], s2);
    }
    #pragma unroll
    for (int off=32; off; off>>=1) {
        s0 += __shfl_down(s0,off); s1 += __shfl_down(s1,off); s2 += __shfl_down(s2,off);
    }
    if (lane == 0) {
        const float* zwl = z_where_last + ((size_t)n*KO + s)*3;
        zwb_all[row*3+0] = fmaxf(s0+bl[0],0.f) + zwl[0];
        zwb_all[row*3+1] = fmaxf(s1+bl[1],0.f) + zwl[1];
        zwb_all[row*3+2] = fmaxf(s2+bl[2],0.f) + zwl[2];
    }
}

__global__ void zero_rin_carry(bf16* __restrict__ rin0) {
    int gid = blockIdx.x*blockDim.x + threadIdx.x;
    if (gid >= NN*309) return;
    int c = gid % 309, n = gid/309;
    int col = (c < 3) ? 103+c : ((c < 53) ? 156+(c-3) : 462+(c-53));
    rin0[(size_t)n*RIN_LD + col] = __float2bfloat16(0.f);
}

// ================= tem LSTM + zwhat + pres (block per n) =================
// zwhat phase reads the TRANSPOSED Wm_wt (wt_t[576][64]): per iteration the wave
// does one coalesced 256B weight load + a wave-uniform LDS broadcast of L.
__global__ __launch_bounds__(256) void tem_fused(
    const float* __restrict__ gates, const float* __restrict__ gates2,
    const float* __restrict__ c_r, const float* __restrict__ h_r,
    const float* __restrict__ z_what_last,
    const float* __restrict__ wt_t, const float* __restrict__ bm_wt,
    const float* __restrict__ Wm_pr, const float* __restrict__ bm_pr,
    const float* __restrict__ Ws_pr, const float* __restrict__ bs_pr,
    const float* __restrict__ zw_cur, const float* __restrict__ z_pres_last,
    float* __restrict__ zwhat_cur, float* __restrict__ out_zwhat,
    float* __restrict__ out_htemp, float* __restrict__ out_zpres,
    bf16* __restrict__ rin_next, int k)
{
    __shared__ float L[615];
    __shared__ float part[4][64];
    int n = blockIdx.x, j = threadIdx.x;
    const float* g  = gates  + (size_t)n*1024;
    const float* g2 = gates2 + (size_t)n*1024;
    float ig = sigm(g[j]       + g2[j]);
    float fg = sigm(g[256+j]   + g2[256+j]);
    float gg = tanhf(g[512+j]  + g2[512+j]);
    float og = sigm(g[768+j]   + g2[768+j]);
    float c2 = fg*c_r[n*256+j] + ig*gg;
    float hv = og*tanhf(c2);
    out_htemp[((size_t)n*KO + k)*HIDD + j] = hv;
    L[309+j] = hv;
    L[53+j]  = h_r[n*256+j];
    if (j < 50)      L[j]  = z_what_last[((size_t)n*KO + k)*50 + j];
    else if (j < 53) L[j]  = zw_cur[n*3 + (j-50)];
    __syncthreads();
    {
        int m = j & 63, grp = j >> 6;
        float sa = 0.f;
        for (int i = grp; i < 562; i += 4) {
            float v = (i < 50) ? L[i] : L[i+3];     // wave-uniform i -> LDS broadcast
            sa = fmaf(v, wt_t[i*64 + m], sa);       // coalesced 256B/wave
        }
        part[grp][m] = sa;
    }
    __syncthreads();
    if (j < 50) {
        float acc = part[0][j] + part[1][j] + part[2][j] + part[3][j] + bm_wt[j];
        zwhat_cur[n*50+j] = acc;
        out_zwhat[((size_t)n*KO + k)*50 + j] = acc;
        rin_next[(size_t)n*RIN_LD + 156 + j] = __float2bfloat16(acc);
        L[565+j] = acc;
    }
    __syncthreads();
    if (j < 64) {
        float s1 = 0.f, s2 = 0.f;
        for (int i = j; i < 565; i += 64) {
            float v = (i < 50) ? L[565+i] : L[i];
            s1 = fmaf(v, Wm_pr[i], s1);
            s2 = fmaf(v, Ws_pr[i], s2);
        }
        #pragma unroll
        for (int off = 32; off; off >>= 1) { s1 += __shfl_down(s1,off); s2 += __shfl_down(s2,off); }
        if (j == 0) {
            float p = sigm(s1 + bm_pr[0]) * sigm(s2 + bs_pr[0]);
            out_zpres[(size_t)n*KO + k] = p * z_pres_last[(size_t)n*KO + k];
        }
    }
}

extern "C" void kernel_launch(void* const* d_in, const int* in_sizes, int n_in,
                              void* d_out, int out_size, void* d_ws, size_t ws_size,
                              hipStream_t stream) {
    (void)in_sizes; (void)n_in; (void)out_size;
    const float* img          = (const float*)d_in[0];
    const float* z_what_last  = (const float*)d_in[1];
    const float* z_where_last = (const float*)d_in[2];
    const float* z_pres_last  = (const float*)d_in[3];
    const float* hidden_last  = (const float*)d_in[4];
    const float* W_loca = (const float*)d_in[5];
    const float* b_loca = (const float*)d_in[6];
    const float* Wg     = (const float*)d_in[7];
    const float* bg     = (const float*)d_in[8];
    const float* Wih_rel = (const float*)d_in[9];
    const float* Whh_rel = (const float*)d_in[10];
    const float* bih_rel = (const float*)d_in[11];
    const float* bhh_rel = (const float*)d_in[12];
    const float* Wih_tem = (const float*)d_in[13];
    const float* Whh_tem = (const float*)d_in[14];
    const float* bih_tem = (const float*)d_in[15];
    const float* bhh_tem = (const float*)d_in[16];
    const float* Wm_wh = (const float*)d_in[17];
    const float* bm_wh = (const float*)d_in[18];
    const float* Wm_wt = (const float*)d_in[21];
    const float* bm_wt = (const float*)d_in[22];
    const float* Wm_pr = (const float*)d_in[25];
    const float* bm_pr = (const float*)d_in[26];
    const float* Ws_pr = (const float*)d_in[27];
    const float* bs_pr = (const float*)d_in[28];

    char* base_p = (char*)d_ws;
    size_t off = 0;
    auto carve = [&](size_t bytes) -> char* {
        char* r = base_p + off;
        off += (bytes + 255) & ~(size_t)255;
        return r;
    };
    bf16*  tin      = (bf16*) carve((size_t)NN*TIN_LD*2);
    float* gates    = (float*)carve((size_t)2*NN*1024*4);   // 2 split-K halves
    bf16*  W_tem    = (bf16*) carve((size_t)1024*TIN_LD*2);
    bf16*  W_rel    = (bf16*) carve((size_t)1024*RIN_LD*2);
    bf16*  Wg_bf    = (bf16*) carve((size_t)100*G1_LD*2);
    float* wt_t     = (float*)carve((size_t)576*64*4);      // transposed Wm_wt
    float* zwb_all  = (float*)carve((size_t)KO*NN*3*4);
    float* h_r      = (float*)carve((size_t)NN*HIDD*4);
    // zero block: c_r, zw1, zwhat1 contiguous
    float* c_r      = (float*)carve((size_t)NN*HIDD*4);
    float* zw1      = (float*)carve((size_t)NN*3*4);
    float* zwhat1   = (float*)carve((size_t)NN*50*4);
    float* zw0      = (float*)carve((size_t)NN*3*4);
    float* zwhat0   = (float*)carve((size_t)NN*50*4);
    size_t fixed_bytes = off;
    float* gates2 = gates + (size_t)NN*1024;

    int CH = 1;
    for (int cand : {8, 4, 2}) {
        size_t need = fixed_bytes
                    + (((size_t)cand*NN*G1_LD*2 + 255) & ~(size_t)255)
                    + (((size_t)cand*NN*RIN_LD*2 + 255) & ~(size_t)255);
        if (need <= ws_size) { CH = cand; break; }
    }
    bf16* g1 = nullptr; int g1ld;
    bf16* rin;
    if (CH > 1) {
        g1   = (bf16*)carve((size_t)CH*NN*G1_LD*2);
        rin  = (bf16*)carve((size_t)CH*NN*RIN_LD*2);
        g1ld = G1_LD;
    } else {
        rin  = (bf16*)carve((size_t)NN*RIN_LD*2);
        g1   = tin;          // glimpse1 -> tin cols 0..2500; Wg pad cols (2500..2560) are zero
        g1ld = TIN_LD;
    }

    float* out        = (float*)d_out;
    float* out_zwhat  = out;
    float* out_zwhere = out + (size_t)NN*KO*50;
    float* out_zpres  = out_zwhere + (size_t)NN*KO*3;
    float* out_htemp  = out_zpres + (size_t)NN*KO;

    // ---- preamble (carry-independent) ----
    {
        int nz = NN*(HIDD + 3 + 50);   // c_r, zw1, zwhat1
        zero_f32<<<(nz+255)/256, 256, 0, stream>>>(c_r, nz);
    }
    zero_rin_carry<<<(NN*309+255)/256, 256, 0, stream>>>(rin);
    repack_w<<<((1024*RIN_LD)+255)/256, 256, 0, stream>>>(Wih_rel, 462, Whh_rel, 256, W_rel, RIN_LD, 1024);
    repack_w<<<((1024*TIN_LD)+255)/256, 256, 0, stream>>>(Wih_tem, 2862, Whh_tem, 256, W_tem, TIN_LD, 1024);
    repack_w<<<((100*G1_LD)+255)/256, 256, 0, stream>>>(Wg, 2500, nullptr, 0, Wg_bf, G1_LD, 100);
    transpose_wmwt<<<(576*64+255)/256, 256, 0, stream>>>(Wm_wt, wt_t);
    zwb_all_v2<<<KO*NN/4, 256, 0, stream>>>(hidden_last, z_where_last, W_loca, b_loca, zwb_all);

    const int GSTR = NN*1024;           // split-K output stride (floats)
    const int KSEG_REL = 384;           // 768/2
    const int KSEG_TEM = 1600;          // ceil(49/2)*64

    for (int cbase = 0; cbase < KO; cbase += CH) {
        // glimpse1 for all CH slices + rin static fill: one block per n, full image in LDS
        glimpse_all<<<NN, 512, 0, stream>>>(img, zwb_all + (size_t)cbase*NN*3, g1, g1ld,
                                            rin, z_where_last, z_what_last, hidden_last, cbase, CH);
        // enc GEMM: 1D swizzled grid, nxb=2, no split
        mfma_gemm<1,1><<<dim3(2*CH*32,1), 256, 0, stream>>>(g1, g1ld, G1_LD, Wg_bf, G1_LD, 100,
                                                            bg, nullptr, rin, RIN_LD, 2, G1_LD, 0);

        for (int s = 0; s < CH; ++s) {
            int k = cbase + s;
            bf16* rin_k  = rin + (size_t)s*NN*RIN_LD;
            bf16* rin_nx = rin + (size_t)((s+1)%CH)*NN*RIN_LD;
            float* zw_cur     = (k & 1) ? zw1 : zw0;
            float* zw_prev    = (k & 1) ? zw0 : zw1;
            float* zwhat_cur  = (k & 1) ? zwhat1 : zwhat0;
            float* zwhat_prev = (k & 1) ? zwhat0 : zwhat1;

            // rel LSTM gates (ih+hh fused, K=768), split-K=2 -> 1024 blocks, 4/CU
            mfma_gemm<0,0><<<dim3(512,2), 256, 0, stream>>>(rin_k, RIN_LD, RIN_LD, W_rel, RIN_LD, 1024,
                                                            bih_rel, bhh_rel, gates, 1024, 16, KSEG_REL, GSTR);
            rel_glimpse2<<<NN, 256, 0, stream>>>(gates, gates2, h_r, c_r, z_where_last, Wm_wh, bm_wh,
                                                 zw_cur, out_zwhere, rin_nx, tin,
                                                 img, zw_prev, zwhat_prev, z_what_last, hidden_last, k);
            // tem LSTM gates (ih+hh fused, K=3136), split-K=2 -> 1024 blocks, 4/CU
            mfma_gemm<0,0><<<dim3(512,2), 256, 0, stream>>>(tin, TIN_LD, TIN_LD, W_tem, TIN_LD, 1024,
                                                            bih_tem, bhh_tem, gates, 1024, 16, KSEG_TEM, GSTR);
            tem_fused<<<NN, 256, 0, stream>>>(gates, gates2, c_r, h_r, z_what_last, wt_t, bm_wt, Wm_pr, bm_pr, Ws_pr, bs_pr,
                                              zw_cur, z_pres_last, zwhat_cur, out_zwhat, out_htemp, out_zpres, rin_nx, k);
        }
    }
}

// Round 5
// 1134.516 us; speedup vs baseline: 1.1706x; 1.0034x over previous
//
#include <hip/hip_runtime.h>
#include <hip/hip_bf16.h>
#include <math.h>

typedef __attribute__((ext_vector_type(8))) short bf16x8;
typedef __attribute__((ext_vector_type(4))) float f32x4;
using bf16 = __hip_bfloat16;

constexpr int NN   = 2048;
constexpr int KO   = 8;
constexpr int IH   = 128, IW = 128;
constexpr int GS   = 50;
constexpr int HIDD = 256;
constexpr int RIN_LD = 768;
constexpr int TIN_LD = 3136;
constexpr int G1_LD  = 2560;
constexpr int GSTR   = NN*1024;      // split-K output stride (floats)

__device__ __forceinline__ float sigm(float x) { return 1.f/(1.f+expf(-x)); }

// ===== MFMA GEMM v4 (64x64 tile) — kept for enc (M=100 needs clamp/masking) =====
template<int OUT_BF16, int RELU>
__global__ __launch_bounds__(256, 4) void mfma_gemm(
    const bf16* __restrict__ A, int lda, int Ktot,
    const bf16* __restrict__ Wt, int ldw, int M,
    const float* __restrict__ b1, const float* __restrict__ b2,
    void* __restrict__ Cout, int ldc, int nxb, int Kseg, int sstride)
{
    __shared__ __align__(16) bf16 As[2*4096];
    __shared__ __align__(16) bf16 Bs[2*4096];
    const int b    = blockIdx.x;
    const int xcd  = b & 7;
    const int t    = b >> 3;
    const int n0   = (xcd + 8*(t / nxb))*64;
    const int m0   = (t % nxb)*64;
    const int tid  = threadIdx.x;
    const int w    = tid>>6, lane = tid&63;
    const int wy   = w>>1, wx = w&1;
    const int q    = lane>>4, fr = lane&15;

    const int kbeg = blockIdx.y * Kseg;
    const int kend = min(Ktot, kbeg + Kseg);
    const int nk   = (kend - kbeg) >> 6;

    const int r0   = tid>>3;
    const int csrc = ((tid&7)*8) ^ ((r0&7)<<3);
    const bf16* pa = A + (size_t)(n0 + r0)*lda + kbeg + csrc;
    int wmr0 = m0 + r0;       if (wmr0 > M-1) wmr0 = M-1;
    int wmr1 = m0 + r0 + 32;  if (wmr1 > M-1) wmr1 = M-1;
    const bf16* pb  = Wt + (size_t)wmr0*ldw + kbeg + csrc;
    const bf16* pb1 = Wt + (size_t)wmr1*ldw + kbeg + csrc;

    f32x4 acc[2][2] = {};

    auto stage = [&](int buf, int koff) {
        bf16* la = As + buf*4096 + w*512;
        bf16* lb = Bs + buf*4096 + w*512;
        __builtin_amdgcn_global_load_lds(
            (const __attribute__((address_space(1))) void*)(pa + koff),
            (__attribute__((address_space(3))) void*)la, 16, 0, 0);
        __builtin_amdgcn_global_load_lds(
            (const __attribute__((address_space(1))) void*)(pa + koff + 32*(size_t)lda),
            (__attribute__((address_space(3))) void*)(la + 2048), 16, 0, 0);
        __builtin_amdgcn_global_load_lds(
            (const __attribute__((address_space(1))) void*)(pb + koff),
            (__attribute__((address_space(3))) void*)lb, 16, 0, 0);
        __builtin_amdgcn_global_load_lds(
            (const __attribute__((address_space(1))) void*)(pb1 + koff),
            (__attribute__((address_space(3))) void*)(lb + 2048), 16, 0, 0);
    };

    stage(0, 0);
    __syncthreads();
    int cur = 0;
    for (int kt = 0; kt < nk; ++kt) {
        if (kt + 1 < nk) stage(cur ^ 1, (kt + 1) << 6);
        const bf16* Ab = As + cur*4096;
        const bf16* Bb = Bs + cur*4096;
        bf16x8 av[2][2], bv[2][2];
        #pragma unroll
        for (int i=0;i<2;i++) {
            int r = wy*32 + i*16 + fr;
            int sw = (r&7)<<3, base = r*64;
            av[i][0] = *(const bf16x8*)(Ab + base + ((q*8) ^ sw));
            av[i][1] = *(const bf16x8*)(Ab + base + ((32 + q*8) ^ sw));
        }
        #pragma unroll
        for (int j=0;j<2;j++) {
            int r = wx*32 + j*16 + fr;
            int sw = (r&7)<<3, base = r*64;
            bv[j][0] = *(const bf16x8*)(Bb + base + ((q*8) ^ sw));
            bv[j][1] = *(const bf16x8*)(Bb + base + ((32 + q*8) ^ sw));
        }
        #pragma unroll
        for (int h=0;h<2;h++)
            #pragma unroll
            for (int i=0;i<2;i++)
                #pragma unroll
                for (int j=0;j<2;j++)
                    acc[i][j] = __builtin_amdgcn_mfma_f32_16x16x32_bf16(av[i][h], bv[j][h], acc[i][j], 0, 0, 0);
        __syncthreads();
        cur ^= 1;
    }

    #pragma unroll
    for (int j=0;j<2;j++) {
        int col = m0 + wx*32 + j*16 + fr;
        if (col < M) {
            float bias = 0.f;
            if (blockIdx.y == 0) {
                if (b1) bias += b1[col];
                if (b2) bias += b2[col];
            }
            #pragma unroll
            for (int i=0;i<2;i++) {
                #pragma unroll
                for (int reg=0;reg<4;reg++) {
                    float v = acc[i][j][reg] + bias;
                    if (RELU) v = fmaxf(v, 0.f);
                    size_t idx = (size_t)(n0 + wy*32 + i*16 + q*4 + reg)*ldc + col;
                    if (OUT_BF16) ((bf16*)Cout)[idx] = __float2bfloat16(v);
                    else          ((float*)Cout)[(size_t)blockIdx.y*sstride + idx] = v;
                }
            }
        }
    }
}

// ===== gemm128: m97-structure 128xBMC tile, BK=64, single-buffer global_load_lds,
// ===== 2-barrier K-step, XOR swizzle both-sides, split-K via grid.y. M must be
// ===== divisible by BMC (rel/tem: M=1024). f32 split output.
template<int JT>   // JT=4 -> BMC=128 ; JT=2 -> BMC=64
__global__ __launch_bounds__(256, 2) void gemm128(
    const bf16* __restrict__ A, int lda, int Ktot,
    const bf16* __restrict__ Wt, int ldw,
    const float* __restrict__ b1, const float* __restrict__ b2,
    float* __restrict__ Cout, int ldc, int nxb, int Kseg, int sstride)
{
    constexpr int BMC = JT*32;
    __shared__ __align__(16) bf16 As[128*64];
    __shared__ __align__(16) bf16 Bs[BMC*64];
    const int b    = blockIdx.x;
    const int xcd  = b & 7;
    const int t    = b >> 3;
    const int n0   = (xcd + 8*(t / nxb))*128;
    const int m0   = (t % nxb)*BMC;
    const int tid  = threadIdx.x;
    const int w    = tid>>6, lane = tid&63;
    const int wy   = w>>1, wx = w&1;
    const int q    = lane>>4, fr = lane&15;

    const int kbeg = blockIdx.y * Kseg;
    const int kend = min(Ktot, kbeg + Kseg);
    const int nk   = (kend - kbeg) >> 6;

    const int r0 = tid>>3;          // 0..31
    const int c0 = (tid&7)*8;

    f32x4 acc[4][JT] = {};

    for (int kt = 0; kt < nk; ++kt) {
        const int koff = kbeg + (kt<<6);
        __syncthreads();                       // previous tile's reads complete
        #pragma unroll
        for (int p=0;p<4;p++) {
            int row = p*32 + r0;
            int csrc = c0 ^ ((row&7)<<3);
            __builtin_amdgcn_global_load_lds(
                (const __attribute__((address_space(1))) void*)(A + (size_t)(n0+row)*lda + koff + csrc),
                (__attribute__((address_space(3))) void*)(As + p*2048 + w*512), 16, 0, 0);
        }
        #pragma unroll
        for (int p=0;p<JT;p++) {
            int row = p*32 + r0;
            int csrc = c0 ^ ((row&7)<<3);
            __builtin_amdgcn_global_load_lds(
                (const __attribute__((address_space(1))) void*)(Wt + (size_t)(m0+row)*ldw + koff + csrc),
                (__attribute__((address_space(3))) void*)(Bs + p*2048 + w*512), 16, 0, 0);
        }
        __syncthreads();                       // drains vmcnt(0): tile staged
        #pragma unroll
        for (int h=0;h<2;h++) {
            bf16x8 av[4], bv[JT];
            #pragma unroll
            for (int i=0;i<4;i++) {
                int r = wy*64 + i*16 + fr;
                av[i] = *(const bf16x8*)(As + r*64 + ((h*32 + q*8) ^ ((r&7)<<3)));
            }
            #pragma unroll
            for (int j=0;j<JT;j++) {
                int r = wx*(JT*16) + j*16 + fr;
                bv[j] = *(const bf16x8*)(Bs + r*64 + ((h*32 + q*8) ^ ((r&7)<<3)));
            }
            #pragma unroll
            for (int i=0;i<4;i++)
                #pragma unroll
                for (int j=0;j<JT;j++)
                    acc[i][j] = __builtin_amdgcn_mfma_f32_16x16x32_bf16(av[i], bv[j], acc[i][j], 0, 0, 0);
        }
    }

    float* Cb = Cout + (size_t)blockIdx.y*sstride;
    #pragma unroll
    for (int j=0;j<JT;j++) {
        int col = m0 + wx*(JT*16) + j*16 + fr;
        float bias = 0.f;
        if (blockIdx.y == 0) {
            if (b1) bias += b1[col];
            if (b2) bias += b2[col];
        }
        #pragma unroll
        for (int i=0;i<4;i++)
            #pragma unroll
            for (int reg=0;reg<4;reg++)
                Cb[(size_t)(n0 + wy*64 + i*16 + q*4 + reg)*ldc + col] = acc[i][j][reg] + bias;
    }
}

// ================= glimpse point math (global-gather path) =================
__device__ __forceinline__ void glimpse_points_global(const float* __restrict__ im,
                                                      float s, float tx, float ty,
                                                      bf16* __restrict__ drow) {
    const float GXS = 2.0f/49.0f;
    const float txp = tx + 1.0f, typ = ty + 1.0f;
    for (int p2 = threadIdx.x; p2 < 1250; p2 += 256) {
        int i = p2 / 25, j = (p2 - i*25)*2;
        float gy  = fmaf((float)i, GXS, -1.0f);
        float py  = fmaf(s, gy, typ)*63.5f;
        float y0f = floorf(py); float fy = py - y0f; int y0 = (int)y0f;
        float wy0 = ((unsigned)y0     < 128u) ? (1.f - fy) : 0.f;
        float wy1 = ((unsigned)(y0+1) < 128u) ? fy         : 0.f;
        const float* r0 = im + min(max(y0,  0),127)*IW;
        const float* r1 = im + min(max(y0+1,0),127)*IW;
        float gxa = fmaf((float)j, GXS, -1.0f);
        float pxa = fmaf(s, gxa, txp)*63.5f;
        float xa0f = floorf(pxa); float fa = pxa - xa0f; int xa0 = (int)xa0f;
        float wa0 = ((unsigned)xa0     < 128u) ? (1.f - fa) : 0.f;
        float wa1 = ((unsigned)(xa0+1) < 128u) ? fa         : 0.f;
        int xa0c = min(max(xa0,  0),127), xa1c = min(max(xa0+1,0),127);
        float gxb = fmaf((float)(j+1), GXS, -1.0f);
        float pxb = fmaf(s, gxb, txp)*63.5f;
        float xb0f = floorf(pxb); float fb = pxb - xb0f; int xb0 = (int)xb0f;
        float wb0 = ((unsigned)xb0     < 128u) ? (1.f - fb) : 0.f;
        float wb1 = ((unsigned)(xb0+1) < 128u) ? fb         : 0.f;
        int xb0c = min(max(xb0,  0),127), xb1c = min(max(xb0+1,0),127);

        float va = fmaf(wy1, fmaf(wa0, r1[xa0c], wa1*r1[xa1c]),
                   wy0 *     fmaf(wa0, r0[xa0c], wa1*r0[xa1c]));
        float vb = fmaf(wy1, fmaf(wb0, r1[xb0c], wb1*r1[xb1c]),
                   wy0 *     fmaf(wb0, r0[xb0c], wb1*r0[xb1c]));

        bf16 b0 = __float2bfloat16(va), b1 = __float2bfloat16(vb);
        unsigned short u0, u1;
        __builtin_memcpy(&u0, &b0, 2); __builtin_memcpy(&u1, &b1, 2);
        *(unsigned int*)(drow + i*GS + j) = (unsigned)u0 | ((unsigned)u1 << 16);
    }
}

// ===== per-point sampler from full-image LDS copy =====
__device__ __forceinline__ void sample_pair_lds(const float* __restrict__ im_s,
                                                float s, float txp, float typ,
                                                int i, int j, bf16* __restrict__ drow) {
    const float GXS = 2.0f/49.0f;
    float gy  = fmaf((float)i, GXS, -1.0f);
    float py  = fmaf(s, gy, typ)*63.5f;
    float y0f = floorf(py); float fy = py - y0f; int y0 = (int)y0f;
    float wy0 = ((unsigned)y0     < 128u) ? (1.f - fy) : 0.f;
    float wy1 = ((unsigned)(y0+1) < 128u) ? fy         : 0.f;
    const float* r0 = im_s + min(max(y0,  0),127)*IW;
    const float* r1 = im_s + min(max(y0+1,0),127)*IW;
    float gxa = fmaf((float)j, GXS, -1.0f);
    float pxa = fmaf(s, gxa, txp)*63.5f;
    float xa0f = floorf(pxa); float fa = pxa - xa0f; int xa0 = (int)xa0f;
    float wa0 = ((unsigned)xa0     < 128u) ? (1.f - fa) : 0.f;
    float wa1 = ((unsigned)(xa0+1) < 128u) ? fa         : 0.f;
    int xa0c = min(max(xa0,  0),127), xa1c = min(max(xa0+1,0),127);
    float gxb = fmaf((float)(j+1), GXS, -1.0f);
    float pxb = fmaf(s, gxb, txp)*63.5f;
    float xb0f = floorf(pxb); float fb = pxb - xb0f; int xb0 = (int)xb0f;
    float wb0 = ((unsigned)xb0     < 128u) ? (1.f - fb) : 0.f;
    float wb1 = ((unsigned)(xb0+1) < 128u) ? fb         : 0.f;
    int xb0c = min(max(xb0,  0),127), xb1c = min(max(xb0+1,0),127);
    float va = fmaf(wy1, fmaf(wa0, r1[xa0c], wa1*r1[xa1c]),
               wy0 *     fmaf(wa0, r0[xa0c], wa1*r0[xa1c]));
    float vb = fmaf(wy1, fmaf(wb0, r1[xb0c], wb1*r1[xb1c]),
               wy0 *     fmaf(wb0, r0[xb0c], wb1*r0[xb1c]));
    bf16 b0 = __float2bfloat16(va), b1 = __float2bfloat16(vb);
    unsigned short u0, u1;
    __builtin_memcpy(&u0, &b0, 2); __builtin_memcpy(&u1, &b1, 2);
    *(unsigned int*)(drow + i*GS + j) = (unsigned)u0 | ((unsigned)u1 << 16);
}

// ========= glimpse1 v2: one block per n; full image in LDS; all CH slices =========
__global__ __launch_bounds__(512) void glimpse_all(const float* __restrict__ img,
                                                   const float* __restrict__ zwb,
                                                   bf16* __restrict__ dst, int ldd,
                                                   bf16* __restrict__ rin,
                                                   const float* __restrict__ z_where_last,
                                                   const float* __restrict__ z_what_last,
                                                   const float* __restrict__ hidden_last,
                                                   int cbase, int CH) {
    __shared__ float im_s[IH*IW];
    const int n = blockIdx.x;
    const float* im = img + (size_t)n*IH*IW;
    {
        const float4* s4 = (const float4*)im;
        float4* d4 = (float4*)im_s;
        #pragma unroll
        for (int t = threadIdx.x; t < IH*IW/4; t += 512) d4[t] = s4[t];
    }
    __syncthreads();

    const int tot = CH*1250;
    for (int p = threadIdx.x; p < tot; p += 512) {
        int sl = p / 1250, p2 = p - sl*1250;
        int i = p2 / 25, j = (p2 - i*25)*2;
        const float* zr = zwb + (size_t)(sl*NN + n)*3;
        float s = zr[0], txp = zr[1] + 1.0f, typ = zr[2] + 1.0f;
        sample_pair_lds(im_s, s, txp, typ, i, j, dst + (size_t)(sl*NN + n)*ldd);
    }

    const int tot2 = CH*309;
    for (int t = threadIdx.x; t < tot2; t += 512) {
        int sl = t / 309, c = t - sl*309;
        int k = cbase + sl;
        bf16* rrow = rin + (size_t)(sl*NN + n)*RIN_LD;
        float v; int col;
        if (c < 3)       { col = 100 + c;      v = z_where_last[((size_t)n*KO + k)*3 + c]; }
        else if (c < 53) { col = 106 + (c-3);  v = z_what_last[((size_t)n*KO + k)*50 + (c-3)]; }
        else             { col = 206 + (c-53); v = hidden_last[((size_t)n*KO + k)*HIDD + (c-53)]; }
        rrow[col] = __float2bfloat16(v);
    }
}

// ===== merged per-step kernel: rel LSTM elementwise + zw linear + glimpse2 + tin fill =====
__global__ __launch_bounds__(256) void rel_glimpse2(
    const float* __restrict__ gates, int nsplit,
    float* __restrict__ h_r, float* __restrict__ c_r,
    const float* __restrict__ z_where_last,
    const float* __restrict__ Wm_wh, const float* __restrict__ bm_wh,
    float* __restrict__ zw_cur, float* __restrict__ out_zwhere,
    bf16* __restrict__ rin_next, bf16* __restrict__ tin,
    const float* __restrict__ img,
    const float* __restrict__ zw_prev, const float* __restrict__ zwhat_prev,
    const float* __restrict__ z_what_last, const float* __restrict__ hidden_last, int k)
{
    __shared__ float hs[256];
    __shared__ float zws[3];
    int n = blockIdx.x, j = threadIdx.x;
    float sI=0.f, sF=0.f, sG=0.f, sO=0.f;
    for (int p = 0; p < nsplit; ++p) {
        const float* g = gates + (size_t)p*GSTR + (size_t)n*1024;
        sI += g[j]; sF += g[256+j]; sG += g[512+j]; sO += g[768+j];
    }
    float ig = sigm(sI), fg = sigm(sF), gg = tanhf(sG), og = sigm(sO);
    int cidx = n*256 + j;
    float c2 = fg*c_r[cidx] + ig*gg;
    float hv = og*tanhf(c2);
    c_r[cidx] = c2;
    h_r[cidx] = hv;
    hs[j] = hv;
    bf16 hb = __float2bfloat16(hv);
    rin_next[(size_t)n*RIN_LD + 462 + j] = hb;
    bf16* trow = tin + (size_t)n*TIN_LD;
    trow[2862 + j] = hb;
    __syncthreads();
    int w = j >> 6, lane = j & 63;
    if (w < 3) {
        const float* wt = Wm_wh + w*259;
        float sa = 0.f;
        for (int i = lane; i < 256; i += 64) sa = fmaf(hs[i], wt[3+i], sa);
        #pragma unroll
        for (int off = 32; off; off >>= 1) sa += __shfl_down(sa, off);
        if (lane == 0) {
            const float* zwl = z_where_last + ((size_t)n*KO + k)*3;
            float acc = bm_wh[w] + sa;
            for (int i = 0; i < 3; i++) acc = fmaf(zwl[i], wt[i], acc);
            zws[w] = acc;
            zw_cur[n*3+w] = acc;
            out_zwhere[((size_t)n*KO + k)*3 + w] = acc;
            bf16 ab = __float2bfloat16(acc);
            rin_next[(size_t)n*RIN_LD + 103 + w] = ab;
            trow[2500 + w] = ab;
        }
    }
    __syncthreads();
    float s = zws[0], tx = zws[1], ty = zws[2];
    glimpse_points_global(img + (size_t)n*IH*IW, s, tx, ty, trow);
    for (int c = 3 + j; c < 362; c += 256) {
        float v;
        if      (c <   6) v = zw_prev[n*3 + c-3];
        else if (c <  56) v = z_what_last[((size_t)n*KO + k)*50 + c-6];
        else if (c < 106) v = zwhat_prev[n*50 + c-56];
        else              v = hidden_last[((size_t)n*KO + k)*HIDD + c-106];
        trow[2500 + c] = __float2bfloat16(v);
    }
}

// ================= small / preamble kernels =================
__global__ void zero_f32(float* __restrict__ p, int n) {
    int i = blockIdx.x*blockDim.x + threadIdx.x;
    if (i < n) p[i] = 0.f;
}

__global__ void repack_w(const float* __restrict__ s1, int K1,
                         const float* __restrict__ s2, int K2,
                         bf16* __restrict__ dst, int ldd, int M) {
    int gid = blockIdx.x*blockDim.x + threadIdx.x;
    if (gid >= M*ldd) return;
    int m = gid / ldd, c = gid - m*ldd;
    float v = 0.f;
    if (c < K1)           v = s1[(size_t)m*K1 + c];
    else if (c < K1+K2)   v = s2[(size_t)m*K2 + (c-K1)];
    dst[gid] = __float2bfloat16(v);
}

// transpose Wm_wt (50 x 562, f32) -> wt_t (576 x 64, f32, zero-padded)
__global__ void transpose_wmwt(const float* __restrict__ W, float* __restrict__ Wt) {
    int gid = blockIdx.x*blockDim.x + threadIdx.x;
    if (gid >= 576*64) return;
    int i = gid >> 6, m = gid & 63;
    Wt[gid] = (m < 50 && i < 562) ? W[(size_t)m*562 + i] : 0.f;
}

__global__ __launch_bounds__(256) void zwb_all_v2(const float* __restrict__ hidden_last,
                                                  const float* __restrict__ z_where_last,
                                                  const float* __restrict__ Wl, const float* __restrict__ bl,
                                                  float* __restrict__ zwb_all) {
    __shared__ float wls[768];
    for (int i = threadIdx.x; i < 768; i += 256) wls[i] = Wl[i];
    __syncthreads();
    int wv = threadIdx.x>>6, lane = threadIdx.x&63;
    int row = blockIdx.x*4 + wv;
    int s = row >> 11, n = row & (NN-1);
    const float* hl = hidden_last + ((size_t)n*KO + s)*HIDD;
    float4 h4 = *(const float4*)(hl + lane*4);
    float s0=0.f, s1=0.f, s2=0.f;
    #pragma unroll
    for (int r4=0;r4<4;r4++) {
        float hv = ((const float*)&h4)[r4];
        int i = lane*4 + r4;
        s0 = fmaf(hv, wls[i],     s0);
        s1 = fmaf(hv, wls[256+i], s1);
        s2 = fmaf(hv, wls[512+i], s2);
    }
    #pragma unroll
    for (int off=32; off; off>>=1) {
        s0 += __shfl_down(s0,off); s1 += __shfl_down(s1,off); s2 += __shfl_down(s2,off);
    }
    if (lane == 0) {
        const float* zwl = z_where_last + ((size_t)n*KO + s)*3;
        zwb_all[row*3+0] = fmaxf(s0+bl[0],0.f) + zwl[0];
        zwb_all[row*3+1] = fmaxf(s1+bl[1],0.f) + zwl[1];
        zwb_all[row*3+2] = fmaxf(s2+bl[2],0.f) + zwl[2];
    }
}

__global__ void zero_rin_carry(bf16* __restrict__ rin0) {
    int gid = blockIdx.x*blockDim.x + threadIdx.x;
    if (gid >= NN*309) return;
    int c = gid % 309, n = gid/309;
    int col = (c < 3) ? 103+c : ((c < 53) ? 156+(c-3) : 462+(c-53));
    rin0[(size_t)n*RIN_LD + col] = __float2bfloat16(0.f);
}

// ================= tem LSTM + zwhat + pres (block per n) =================
__global__ __launch_bounds__(256) void tem_fused(
    const float* __restrict__ gates, int nsplit,
    const float* __restrict__ c_r, const float* __restrict__ h_r,
    const float* __restrict__ z_what_last,
    const float* __restrict__ wt_t, const float* __restrict__ bm_wt,
    const float* __restrict__ Wm_pr, const float* __restrict__ bm_pr,
    const float* __restrict__ Ws_pr, const float* __restrict__ bs_pr,
    const float* __restrict__ zw_cur, const float* __restrict__ z_pres_last,
    float* __restrict__ zwhat_cur, float* __restrict__ out_zwhat,
    float* __restrict__ out_htemp, float* __restrict__ out_zpres,
    bf16* __restrict__ rin_next, int k)
{
    __shared__ float L[615];
    __shared__ float part[4][64];
    int n = blockIdx.x, j = threadIdx.x;
    float sI=0.f, sF=0.f, sG=0.f, sO=0.f;
    for (int p = 0; p < nsplit; ++p) {
        const float* g = gates + (size_t)p*GSTR + (size_t)n*1024;
        sI += g[j]; sF += g[256+j]; sG += g[512+j]; sO += g[768+j];
    }
    float ig = sigm(sI), fg = sigm(sF), gg = tanhf(sG), og = sigm(sO);
    float c2 = fg*c_r[n*256+j] + ig*gg;
    float hv = og*tanhf(c2);
    out_htemp[((size_t)n*KO + k)*HIDD + j] = hv;
    L[309+j] = hv;
    L[53+j]  = h_r[n*256+j];
    if (j < 50)      L[j]  = z_what_last[((size_t)n*KO + k)*50 + j];
    else if (j < 53) L[j]  = zw_cur[n*3 + (j-50)];
    __syncthreads();
    {
        int m = j & 63, grp = j >> 6;
        float sa = 0.f;
        for (int i = grp; i < 562; i += 4) {
            float v = (i < 50) ? L[i] : L[i+3];
            sa = fmaf(v, wt_t[i*64 + m], sa);
        }
        part[grp][m] = sa;
    }
    __syncthreads();
    if (j < 50) {
        float acc = part[0][j] + part[1][j] + part[2][j] + part[3][j] + bm_wt[j];
        zwhat_cur[n*50+j] = acc;
        out_zwhat[((size_t)n*KO + k)*50 + j] = acc;
        rin_next[(size_t)n*RIN_LD + 156 + j] = __float2bfloat16(acc);
        L[565+j] = acc;
    }
    __syncthreads();
    if (j < 64) {
        float s1 = 0.f, s2 = 0.f;
        for (int i = j; i < 565; i += 64) {
            float v = (i < 50) ? L[565+i] : L[i];
            s1 = fmaf(v, Wm_pr[i], s1);
            s2 = fmaf(v, Ws_pr[i], s2);
        }
        #pragma unroll
        for (int off = 32; off; off >>= 1) { s1 += __shfl_down(s1,off); s2 += __shfl_down(s2,off); }
        if (j == 0) {
            float p = sigm(s1 + bm_pr[0]) * sigm(s2 + bs_pr[0]);
            out_zpres[(size_t)n*KO + k] = p * z_pres_last[(size_t)n*KO + k];
        }
    }
}

extern "C" void kernel_launch(void* const* d_in, const int* in_sizes, int n_in,
                              void* d_out, int out_size, void* d_ws, size_t ws_size,
                              hipStream_t stream) {
    (void)in_sizes; (void)n_in; (void)out_size;
    const float* img          = (const float*)d_in[0];
    const float* z_what_last  = (const float*)d_in[1];
    const float* z_where_last = (const float*)d_in[2];
    const float* z_pres_last  = (const float*)d_in[3];
    const float* hidden_last  = (const float*)d_in[4];
    const float* W_loca = (const float*)d_in[5];
    const float* b_loca = (const float*)d_in[6];
    const float* Wg     = (const float*)d_in[7];
    const float* bg     = (const float*)d_in[8];
    const float* Wih_rel = (const float*)d_in[9];
    const float* Whh_rel = (const float*)d_in[10];
    const float* bih_rel = (const float*)d_in[11];
    const float* bhh_rel = (const float*)d_in[12];
    const float* Wih_tem = (const float*)d_in[13];
    const float* Whh_tem = (const float*)d_in[14];
    const float* bih_tem = (const float*)d_in[15];
    const float* bhh_tem = (const float*)d_in[16];
    const float* Wm_wh = (const float*)d_in[17];
    const float* bm_wh = (const float*)d_in[18];
    const float* Wm_wt = (const float*)d_in[21];
    const float* bm_wt = (const float*)d_in[22];
    const float* Wm_pr = (const float*)d_in[25];
    const float* bm_pr = (const float*)d_in[26];
    const float* Ws_pr = (const float*)d_in[27];
    const float* bs_pr = (const float*)d_in[28];

    char* base_p = (char*)d_ws;
    size_t off = 0;
    auto carve = [&](size_t bytes) -> char* {
        char* r = base_p + off;
        off += (bytes + 255) & ~(size_t)255;
        return r;
    };
    bf16*  tin      = (bf16*) carve((size_t)NN*TIN_LD*2);
    float* gates    = (float*)carve((size_t)4*NN*1024*4);   // up to 4 split-K partials
    bf16*  W_tem    = (bf16*) carve((size_t)1024*TIN_LD*2);
    bf16*  W_rel    = (bf16*) carve((size_t)1024*RIN_LD*2);
    bf16*  Wg_bf    = (bf16*) carve((size_t)100*G1_LD*2);
    float* wt_t     = (float*)carve((size_t)576*64*4);
    float* zwb_all  = (float*)carve((size_t)KO*NN*3*4);
    float* h_r      = (float*)carve((size_t)NN*HIDD*4);
    float* c_r      = (float*)carve((size_t)NN*HIDD*4);
    float* zw1      = (float*)carve((size_t)NN*3*4);
    float* zwhat1   = (float*)carve((size_t)NN*50*4);
    float* zw0      = (float*)carve((size_t)NN*3*4);
    float* zwhat0   = (float*)carve((size_t)NN*50*4);
    size_t fixed_bytes = off;

    int CH = 1;
    for (int cand : {8, 4, 2}) {
        size_t need = fixed_bytes
                    + (((size_t)cand*NN*G1_LD*2 + 255) & ~(size_t)255)
                    + (((size_t)cand*NN*RIN_LD*2 + 255) & ~(size_t)255);
        if (need <= ws_size) { CH = cand; break; }
    }
    bf16* g1 = nullptr; int g1ld;
    bf16* rin;
    if (CH > 1) {
        g1   = (bf16*)carve((size_t)CH*NN*G1_LD*2);
        rin  = (bf16*)carve((size_t)CH*NN*RIN_LD*2);
        g1ld = G1_LD;
    } else {
        rin  = (bf16*)carve((size_t)NN*RIN_LD*2);
        g1   = tin;
        g1ld = TIN_LD;
    }

    float* out        = (float*)d_out;
    float* out_zwhat  = out;
    float* out_zwhere = out + (size_t)NN*KO*50;
    float* out_zpres  = out_zwhere + (size_t)NN*KO*3;
    float* out_htemp  = out_zpres + (size_t)NN*KO;

    // ---- preamble ----
    {
        int nz = NN*(HIDD + 3 + 50);
        zero_f32<<<(nz+255)/256, 256, 0, stream>>>(c_r, nz);
    }
    zero_rin_carry<<<(NN*309+255)/256, 256, 0, stream>>>(rin);
    repack_w<<<((1024*RIN_LD)+255)/256, 256, 0, stream>>>(Wih_rel, 462, Whh_rel, 256, W_rel, RIN_LD, 1024);
    repack_w<<<((1024*TIN_LD)+255)/256, 256, 0, stream>>>(Wih_tem, 2862, Whh_tem, 256, W_tem, TIN_LD, 1024);
    repack_w<<<((100*G1_LD)+255)/256, 256, 0, stream>>>(Wg, 2500, nullptr, 0, Wg_bf, G1_LD, 100);
    transpose_wmwt<<<(576*64+255)/256, 256, 0, stream>>>(Wm_wt, wt_t);
    zwb_all_v2<<<KO*NN/4, 256, 0, stream>>>(hidden_last, z_where_last, W_loca, b_loca, zwb_all);

    for (int cbase = 0; cbase < KO; cbase += CH) {
        glimpse_all<<<NN, 512, 0, stream>>>(img, zwb_all + (size_t)cbase*NN*3, g1, g1ld,
                                            rin, z_where_last, z_what_last, hidden_last, cbase, CH);
        // enc GEMM (M=100): v4 64² path
        mfma_gemm<1,1><<<dim3(2*CH*32,1), 256, 0, stream>>>(g1, g1ld, G1_LD, Wg_bf, G1_LD, 100,
                                                            bg, nullptr, rin, RIN_LD, 2, G1_LD, 0);

        for (int s = 0; s < CH; ++s) {
            int k = cbase + s;
            bf16* rin_k  = rin + (size_t)s*NN*RIN_LD;
            bf16* rin_nx = rin + (size_t)((s+1)%CH)*NN*RIN_LD;
            float* zw_cur     = (k & 1) ? zw1 : zw0;
            float* zw_prev    = (k & 1) ? zw0 : zw1;
            float* zwhat_cur  = (k & 1) ? zwhat1 : zwhat0;
            float* zwhat_prev = (k & 1) ? zwhat0 : zwhat1;

            // rel LSTM gates: 128x64 tile, split-K=2 -> 512 blocks, 2/CU
            gemm128<2><<<dim3(256,2), 256, 0, stream>>>(rin_k, RIN_LD, RIN_LD, W_rel, RIN_LD,
                                                        bih_rel, bhh_rel, gates, 1024, 16, 384, GSTR);
            rel_glimpse2<<<NN, 256, 0, stream>>>(gates, 2, h_r, c_r, z_where_last, Wm_wh, bm_wh,
                                                 zw_cur, out_zwhere, rin_nx, tin,
                                                 img, zw_prev, zwhat_prev, z_what_last, hidden_last, k);
            // tem LSTM gates: 128x128 tile, split-K=4 -> 512 blocks, 2/CU
            gemm128<4><<<dim3(128,4), 256, 0, stream>>>(tin, TIN_LD, TIN_LD, W_tem, TIN_LD,
                                                        bih_tem, bhh_tem, gates, 1024, 8, 832, GSTR);
            tem_fused<<<NN, 256, 0, stream>>>(gates, 4, c_r, h_r, z_what_last, wt_t, bm_wt, Wm_pr, bm_pr, Ws_pr, bs_pr,
                                              zw_cur, z_pres_last, zwhat_cur, out_zwhat, out_htemp, out_zpres, rin_nx, k);
        }
    }
}

// Round 6
// 1125.555 us; speedup vs baseline: 1.1799x; 1.0080x over previous
//
#include <hip/hip_runtime.h>
#include <hip/hip_bf16.h>
#include <math.h>

typedef __attribute__((ext_vector_type(8))) short bf16x8;
typedef __attribute__((ext_vector_type(4))) float f32x4;
using bf16 = __hip_bfloat16;

constexpr int NN   = 2048;
constexpr int KO   = 8;
constexpr int IH   = 128, IW = 128;
constexpr int GS   = 50;
constexpr int HIDD = 256;
constexpr int RIN_LD = 768;
constexpr int TIN_LD = 3136;
constexpr int G1_LD  = 2560;
constexpr int GSTR   = NN*1024;      // split-K output stride (floats)

__device__ __forceinline__ float sigm(float x) { return 1.f/(1.f+expf(-x)); }

// ===== MFMA GEMM v4 (64x64 tile) — kept for enc (M=100 needs clamp/masking) =====
template<int OUT_BF16, int RELU>
__global__ __launch_bounds__(256, 4) void mfma_gemm(
    const bf16* __restrict__ A, int lda, int Ktot,
    const bf16* __restrict__ Wt, int ldw, int M,
    const float* __restrict__ b1, const float* __restrict__ b2,
    void* __restrict__ Cout, int ldc, int nxb, int Kseg, int sstride)
{
    __shared__ __align__(16) bf16 As[2*4096];
    __shared__ __align__(16) bf16 Bs[2*4096];
    const int b    = blockIdx.x;
    const int xcd  = b & 7;
    const int t    = b >> 3;
    const int n0   = (xcd + 8*(t / nxb))*64;
    const int m0   = (t % nxb)*64;
    const int tid  = threadIdx.x;
    const int w    = tid>>6, lane = tid&63;
    const int wy   = w>>1, wx = w&1;
    const int q    = lane>>4, fr = lane&15;

    const int kbeg = blockIdx.y * Kseg;
    const int kend = min(Ktot, kbeg + Kseg);
    const int nk   = (kend - kbeg) >> 6;

    const int r0   = tid>>3;
    const int csrc = ((tid&7)*8) ^ ((r0&7)<<3);
    const bf16* pa = A + (size_t)(n0 + r0)*lda + kbeg + csrc;
    int wmr0 = m0 + r0;       if (wmr0 > M-1) wmr0 = M-1;
    int wmr1 = m0 + r0 + 32;  if (wmr1 > M-1) wmr1 = M-1;
    const bf16* pb  = Wt + (size_t)wmr0*ldw + kbeg + csrc;
    const bf16* pb1 = Wt + (size_t)wmr1*ldw + kbeg + csrc;

    f32x4 acc[2][2] = {};

    auto stage = [&](int buf, int koff) {
        bf16* la = As + buf*4096 + w*512;
        bf16* lb = Bs + buf*4096 + w*512;
        __builtin_amdgcn_global_load_lds(
            (const __attribute__((address_space(1))) void*)(pa + koff),
            (__attribute__((address_space(3))) void*)la, 16, 0, 0);
        __builtin_amdgcn_global_load_lds(
            (const __attribute__((address_space(1))) void*)(pa + koff + 32*(size_t)lda),
            (__attribute__((address_space(3))) void*)(la + 2048), 16, 0, 0);
        __builtin_amdgcn_global_load_lds(
            (const __attribute__((address_space(1))) void*)(pb + koff),
            (__attribute__((address_space(3))) void*)lb, 16, 0, 0);
        __builtin_amdgcn_global_load_lds(
            (const __attribute__((address_space(1))) void*)(pb1 + koff),
            (__attribute__((address_space(3))) void*)(lb + 2048), 16, 0, 0);
    };

    stage(0, 0);
    __syncthreads();
    int cur = 0;
    for (int kt = 0; kt < nk; ++kt) {
        if (kt + 1 < nk) stage(cur ^ 1, (kt + 1) << 6);
        const bf16* Ab = As + cur*4096;
        const bf16* Bb = Bs + cur*4096;
        bf16x8 av[2][2], bv[2][2];
        #pragma unroll
        for (int i=0;i<2;i++) {
            int r = wy*32 + i*16 + fr;
            int sw = (r&7)<<3, base = r*64;
            av[i][0] = *(const bf16x8*)(Ab + base + ((q*8) ^ sw));
            av[i][1] = *(const bf16x8*)(Ab + base + ((32 + q*8) ^ sw));
        }
        #pragma unroll
        for (int j=0;j<2;j++) {
            int r = wx*32 + j*16 + fr;
            int sw = (r&7)<<3, base = r*64;
            bv[j][0] = *(const bf16x8*)(Bb + base + ((q*8) ^ sw));
            bv[j][1] = *(const bf16x8*)(Bb + base + ((32 + q*8) ^ sw));
        }
        #pragma unroll
        for (int h=0;h<2;h++)
            #pragma unroll
            for (int i=0;i<2;i++)
                #pragma unroll
                for (int j=0;j<2;j++)
                    acc[i][j] = __builtin_amdgcn_mfma_f32_16x16x32_bf16(av[i][h], bv[j][h], acc[i][j], 0, 0, 0);
        __syncthreads();
        cur ^= 1;
    }

    #pragma unroll
    for (int j=0;j<2;j++) {
        int col = m0 + wx*32 + j*16 + fr;
        if (col < M) {
            float bias = 0.f;
            if (blockIdx.y == 0) {
                if (b1) bias += b1[col];
                if (b2) bias += b2[col];
            }
            #pragma unroll
            for (int i=0;i<2;i++) {
                #pragma unroll
                for (int reg=0;reg<4;reg++) {
                    float v = acc[i][j][reg] + bias;
                    if (RELU) v = fmaxf(v, 0.f);
                    size_t idx = (size_t)(n0 + wy*32 + i*16 + q*4 + reg)*ldc + col;
                    if (OUT_BF16) ((bf16*)Cout)[idx] = __float2bfloat16(v);
                    else          ((float*)Cout)[(size_t)blockIdx.y*sstride + idx] = v;
                }
            }
        }
    }
}

// ===== gemm128: 128xBMC tile, BK=64, single-buffer global_load_lds, split-K via grid.y =====
template<int JT>   // JT=4 -> BMC=128 ; JT=2 -> BMC=64
__global__ __launch_bounds__(256, 2) void gemm128(
    const bf16* __restrict__ A, int lda, int Ktot,
    const bf16* __restrict__ Wt, int ldw,
    const float* __restrict__ b1, const float* __restrict__ b2,
    float* __restrict__ Cout, int ldc, int nxb, int Kseg, int sstride)
{
    constexpr int BMC = JT*32;
    __shared__ __align__(16) bf16 As[128*64];
    __shared__ __align__(16) bf16 Bs[BMC*64];
    const int b    = blockIdx.x;
    const int xcd  = b & 7;
    const int t    = b >> 3;
    const int n0   = (xcd + 8*(t / nxb))*128;
    const int m0   = (t % nxb)*BMC;
    const int tid  = threadIdx.x;
    const int w    = tid>>6, lane = tid&63;
    const int wy   = w>>1, wx = w&1;
    const int q    = lane>>4, fr = lane&15;

    const int kbeg = blockIdx.y * Kseg;
    const int kend = min(Ktot, kbeg + Kseg);
    const int nk   = (kend - kbeg) >> 6;

    const int r0 = tid>>3;          // 0..31
    const int c0 = (tid&7)*8;

    f32x4 acc[4][JT] = {};

    for (int kt = 0; kt < nk; ++kt) {
        const int koff = kbeg + (kt<<6);
        __syncthreads();
        #pragma unroll
        for (int p=0;p<4;p++) {
            int row = p*32 + r0;
            int csrc = c0 ^ ((row&7)<<3);
            __builtin_amdgcn_global_load_lds(
                (const __attribute__((address_space(1))) void*)(A + (size_t)(n0+row)*lda + koff + csrc),
                (__attribute__((address_space(3))) void*)(As + p*2048 + w*512), 16, 0, 0);
        }
        #pragma unroll
        for (int p=0;p<JT;p++) {
            int row = p*32 + r0;
            int csrc = c0 ^ ((row&7)<<3);
            __builtin_amdgcn_global_load_lds(
                (const __attribute__((address_space(1))) void*)(Wt + (size_t)(m0+row)*ldw + koff + csrc),
                (__attribute__((address_space(3))) void*)(Bs + p*2048 + w*512), 16, 0, 0);
        }
        __syncthreads();
        #pragma unroll
        for (int h=0;h<2;h++) {
            bf16x8 av[4], bv[JT];
            #pragma unroll
            for (int i=0;i<4;i++) {
                int r = wy*64 + i*16 + fr;
                av[i] = *(const bf16x8*)(As + r*64 + ((h*32 + q*8) ^ ((r&7)<<3)));
            }
            #pragma unroll
            for (int j=0;j<JT;j++) {
                int r = wx*(JT*16) + j*16 + fr;
                bv[j] = *(const bf16x8*)(Bs + r*64 + ((h*32 + q*8) ^ ((r&7)<<3)));
            }
            #pragma unroll
            for (int i=0;i<4;i++)
                #pragma unroll
                for (int j=0;j<JT;j++)
                    acc[i][j] = __builtin_amdgcn_mfma_f32_16x16x32_bf16(av[i], bv[j], acc[i][j], 0, 0, 0);
        }
    }

    float* Cb = Cout + (size_t)blockIdx.y*sstride;
    #pragma unroll
    for (int j=0;j<JT;j++) {
        int col = m0 + wx*(JT*16) + j*16 + fr;
        float bias = 0.f;
        if (blockIdx.y == 0) {
            if (b1) bias += b1[col];
            if (b2) bias += b2[col];
        }
        #pragma unroll
        for (int i=0;i<4;i++)
            #pragma unroll
            for (int reg=0;reg<4;reg++)
                Cb[(size_t)(n0 + wy*64 + i*16 + q*4 + reg)*ldc + col] = acc[i][j][reg] + bias;
    }
}

// ========= glimpse1 v3: one block per n; full image + per-slice x/y interp TABLES in LDS.
// ========= Table factoring is bit-exact: identical FMA formulas, computed once per sample.
__global__ __launch_bounds__(512) void glimpse_all(const float* __restrict__ img,
                                                   const float* __restrict__ zwb,
                                                   bf16* __restrict__ dst, int ldd,
                                                   bf16* __restrict__ rin,
                                                   const float* __restrict__ z_where_last,
                                                   const float* __restrict__ z_what_last,
                                                   const float* __restrict__ hidden_last,
                                                   int cbase, int CH) {
    __shared__ float im_s[IH*IW];            // 64 KB
    __shared__ float xw0[KO*50], xw1[KO*50];
    __shared__ int   xi0[KO*50], xi1[KO*50];
    __shared__ float yw0[KO*50], yw1[KO*50];
    __shared__ int   yr0[KO*50], yr1[KO*50]; // tables 12.8 KB -> still 2 blocks/CU
    const int n = blockIdx.x;
    const float* im = img + (size_t)n*IH*IW;
    {
        const float4* s4 = (const float4*)im;
        float4* d4 = (float4*)im_s;
        for (int t = threadIdx.x; t < IH*IW/4; t += 512) d4[t] = s4[t];
    }
    const float GXS = 2.0f/49.0f;
    for (int t = threadIdx.x; t < CH*100; t += 512) {
        int sl = t / 100, r = t - sl*100;
        const float* zr = zwb + (size_t)(sl*NN + n)*3;
        float s = zr[0];
        if (r < 50) {
            float txp = zr[1] + 1.0f;
            float gx = fmaf((float)r, GXS, -1.0f);
            float px = fmaf(s, gx, txp)*63.5f;
            float x0f = floorf(px); float fa = px - x0f; int x0 = (int)x0f;
            xw0[sl*50+r] = ((unsigned)x0     < 128u) ? (1.f - fa) : 0.f;
            xw1[sl*50+r] = ((unsigned)(x0+1) < 128u) ? fa         : 0.f;
            xi0[sl*50+r] = min(max(x0,  0),127);
            xi1[sl*50+r] = min(max(x0+1,0),127);
        } else {
            int i = r - 50;
            float typ = zr[2] + 1.0f;
            float gy = fmaf((float)i, GXS, -1.0f);
            float py = fmaf(s, gy, typ)*63.5f;
            float y0f = floorf(py); float fy = py - y0f; int y0 = (int)y0f;
            yw0[sl*50+i] = ((unsigned)y0     < 128u) ? (1.f - fy) : 0.f;
            yw1[sl*50+i] = ((unsigned)(y0+1) < 128u) ? fy         : 0.f;
            yr0[sl*50+i] = min(max(y0,  0),127)*IW;
            yr1[sl*50+i] = min(max(y0+1,0),127)*IW;
        }
    }
    __syncthreads();

    const int tot = CH*1250;
    for (int p = threadIdx.x; p < tot; p += 512) {
        int sl = p / 1250, p2 = p - sl*1250;
        int i = p2 / 25, j = (p2 - i*25)*2;
        const float* r0 = im_s + yr0[sl*50+i];
        const float* r1 = im_s + yr1[sl*50+i];
        float wy0 = yw0[sl*50+i], wy1 = yw1[sl*50+i];
        int   a0 = xi0[sl*50+j],     a1 = xi1[sl*50+j];
        float wa0 = xw0[sl*50+j],    wa1 = xw1[sl*50+j];
        int   e0 = xi0[sl*50+j+1],   e1 = xi1[sl*50+j+1];
        float wb0 = xw0[sl*50+j+1],  wb1 = xw1[sl*50+j+1];
        float va = fmaf(wy1, fmaf(wa0, r1[a0], wa1*r1[a1]),
                   wy0 *     fmaf(wa0, r0[a0], wa1*r0[a1]));
        float vb = fmaf(wy1, fmaf(wb0, r1[e0], wb1*r1[e1]),
                   wy0 *     fmaf(wb0, r0[e0], wb1*r0[e1]));
        bf16 b0 = __float2bfloat16(va), b1 = __float2bfloat16(vb);
        unsigned short u0, u1;
        __builtin_memcpy(&u0, &b0, 2); __builtin_memcpy(&u1, &b1, 2);
        bf16* drow = dst + (size_t)(sl*NN + n)*ldd;
        *(unsigned int*)(drow + i*GS + j) = (unsigned)u0 | ((unsigned)u1 << 16);
    }

    const int tot2 = CH*309;
    for (int t = threadIdx.x; t < tot2; t += 512) {
        int sl = t / 309, c = t - sl*309;
        int k = cbase + sl;
        bf16* rrow = rin + (size_t)(sl*NN + n)*RIN_LD;
        float v; int col;
        if (c < 3)       { col = 100 + c;      v = z_where_last[((size_t)n*KO + k)*3 + c]; }
        else if (c < 53) { col = 106 + (c-3);  v = z_what_last[((size_t)n*KO + k)*50 + (c-3)]; }
        else             { col = 206 + (c-53); v = hidden_last[((size_t)n*KO + k)*HIDD + (c-53)]; }
        rrow[col] = __float2bfloat16(v);
    }
}

// ===== merged per-step kernel: rel LSTM elementwise + zw linear + glimpse2 (table) + tin fill =====
__global__ __launch_bounds__(256) void rel_glimpse2(
    const float* __restrict__ gates, int nsplit,
    float* __restrict__ h_r, float* __restrict__ c_r,
    const float* __restrict__ z_where_last,
    const float* __restrict__ Wm_wh, const float* __restrict__ bm_wh,
    float* __restrict__ zw_cur, float* __restrict__ out_zwhere,
    bf16* __restrict__ rin_next, bf16* __restrict__ tin,
    const float* __restrict__ img,
    const float* __restrict__ zw_prev, const float* __restrict__ zwhat_prev,
    const float* __restrict__ z_what_last, const float* __restrict__ hidden_last, int k)
{
    __shared__ float hs[256];
    __shared__ float zws[3];
    __shared__ float xw0[50], xw1[50], yw0[50], yw1[50];
    __shared__ int   xi0[50], xi1[50], yr0[50], yr1[50];
    int n = blockIdx.x, j = threadIdx.x;
    float sI=0.f, sF=0.f, sG=0.f, sO=0.f;
    for (int p = 0; p < nsplit; ++p) {
        const float* g = gates + (size_t)p*GSTR + (size_t)n*1024;
        sI += g[j]; sF += g[256+j]; sG += g[512+j]; sO += g[768+j];
    }
    float ig = sigm(sI), fg = sigm(sF), gg = tanhf(sG), og = sigm(sO);
    int cidx = n*256 + j;
    float c2 = fg*c_r[cidx] + ig*gg;
    float hv = og*tanhf(c2);
    c_r[cidx] = c2;
    h_r[cidx] = hv;
    hs[j] = hv;
    bf16 hb = __float2bfloat16(hv);
    rin_next[(size_t)n*RIN_LD + 462 + j] = hb;
    bf16* trow = tin + (size_t)n*TIN_LD;
    trow[2862 + j] = hb;
    __syncthreads();
    int w = j >> 6, lane = j & 63;
    if (w < 3) {
        const float* wt = Wm_wh + w*259;
        float sa = 0.f;
        for (int i = lane; i < 256; i += 64) sa = fmaf(hs[i], wt[3+i], sa);
        #pragma unroll
        for (int off = 32; off; off >>= 1) sa += __shfl_down(sa, off);
        if (lane == 0) {
            const float* zwl = z_where_last + ((size_t)n*KO + k)*3;
            float acc = bm_wh[w] + sa;
            for (int i = 0; i < 3; i++) acc = fmaf(zwl[i], wt[i], acc);
            zws[w] = acc;
            zw_cur[n*3+w] = acc;
            out_zwhere[((size_t)n*KO + k)*3 + w] = acc;
            bf16 ab = __float2bfloat16(acc);
            rin_next[(size_t)n*RIN_LD + 103 + w] = ab;
            trow[2500 + w] = ab;
        }
    }
    __syncthreads();
    // build interp tables (bit-exact factoring of the per-pair formulas)
    {
        const float GXS = 2.0f/49.0f;
        float s = zws[0];
        if (j < 50) {
            float txp = zws[1] + 1.0f;
            float gx = fmaf((float)j, GXS, -1.0f);
            float px = fmaf(s, gx, txp)*63.5f;
            float x0f = floorf(px); float fa = px - x0f; int x0 = (int)x0f;
            xw0[j] = ((unsigned)x0     < 128u) ? (1.f - fa) : 0.f;
            xw1[j] = ((unsigned)(x0+1) < 128u) ? fa         : 0.f;
            xi0[j] = min(max(x0,  0),127);
            xi1[j] = min(max(x0+1,0),127);
        } else if (j < 100) {
            int i = j - 50;
            float typ = zws[2] + 1.0f;
            float gy = fmaf((float)i, GXS, -1.0f);
            float py = fmaf(s, gy, typ)*63.5f;
            float y0f = floorf(py); float fy = py - y0f; int y0 = (int)y0f;
            yw0[i] = ((unsigned)y0     < 128u) ? (1.f - fy) : 0.f;
            yw1[i] = ((unsigned)(y0+1) < 128u) ? fy         : 0.f;
            yr0[i] = min(max(y0,  0),127)*IW;
            yr1[i] = min(max(y0+1,0),127)*IW;
        }
    }
    __syncthreads();
    const float* im = img + (size_t)n*IH*IW;
    for (int p2 = j; p2 < 1250; p2 += 256) {
        int i = p2 / 25, jj = (p2 - i*25)*2;
        const float* r0 = im + yr0[i];
        const float* r1 = im + yr1[i];
        float wy0 = yw0[i], wy1 = yw1[i];
        int   a0 = xi0[jj],    a1 = xi1[jj];
        float wa0 = xw0[jj],   wa1 = xw1[jj];
        int   e0 = xi0[jj+1],  e1 = xi1[jj+1];
        float wb0 = xw0[jj+1], wb1 = xw1[jj+1];
        float va = fmaf(wy1, fmaf(wa0, r1[a0], wa1*r1[a1]),
                   wy0 *     fmaf(wa0, r0[a0], wa1*r0[a1]));
        float vb = fmaf(wy1, fmaf(wb0, r1[e0], wb1*r1[e1]),
                   wy0 *     fmaf(wb0, r0[e0], wb1*r0[e1]));
        bf16 b0 = __float2bfloat16(va), b1 = __float2bfloat16(vb);
        unsigned short u0, u1;
        __builtin_memcpy(&u0, &b0, 2); __builtin_memcpy(&u1, &b1, 2);
        *(unsigned int*)(trow + i*GS + jj) = (unsigned)u0 | ((unsigned)u1 << 16);
    }
    for (int c = 3 + j; c < 362; c += 256) {
        float v;
        if      (c <   6) v = zw_prev[n*3 + c-3];
        else if (c <  56) v = z_what_last[((size_t)n*KO + k)*50 + c-6];
        else if (c < 106) v = zwhat_prev[n*50 + c-56];
        else              v = hidden_last[((size_t)n*KO + k)*HIDD + c-106];
        trow[2500 + c] = __float2bfloat16(v);
    }
}

// ================= small / preamble kernels =================
__global__ void zero_f32(float* __restrict__ p, int n) {
    int i = blockIdx.x*blockDim.x + threadIdx.x;
    if (i < n) p[i] = 0.f;
}

__global__ void repack_w(const float* __restrict__ s1, int K1,
                         const float* __restrict__ s2, int K2,
                         bf16* __restrict__ dst, int ldd, int M) {
    int gid = blockIdx.x*blockDim.x + threadIdx.x;
    if (gid >= M*ldd) return;
    int m = gid / ldd, c = gid - m*ldd;
    float v = 0.f;
    if (c < K1)           v = s1[(size_t)m*K1 + c];
    else if (c < K1+K2)   v = s2[(size_t)m*K2 + (c-K1)];
    dst[gid] = __float2bfloat16(v);
}

// transpose Wm_wt (50 x 562, f32) -> wt_t (576 x 64, f32, zero-padded)
__global__ void transpose_wmwt(const float* __restrict__ W, float* __restrict__ Wt) {
    int gid = blockIdx.x*blockDim.x + threadIdx.x;
    if (gid >= 576*64) return;
    int i = gid >> 6, m = gid & 63;
    Wt[gid] = (m < 50 && i < 562) ? W[(size_t)m*562 + i] : 0.f;
}

__global__ __launch_bounds__(256) void zwb_all_v2(const float* __restrict__ hidden_last,
                                                  const float* __restrict__ z_where_last,
                                                  const float* __restrict__ Wl, const float* __restrict__ bl,
                                                  float* __restrict__ zwb_all) {
    __shared__ float wls[768];
    for (int i = threadIdx.x; i < 768; i += 256) wls[i] = Wl[i];
    __syncthreads();
    int wv = threadIdx.x>>6, lane = threadIdx.x&63;
    int row = blockIdx.x*4 + wv;
    int s = row >> 11, n = row & (NN-1);
    const float* hl = hidden_last + ((size_t)n*KO + s)*HIDD;
    float4 h4 = *(const float4*)(hl + lane*4);
    float s0=0.f, s1=0.f, s2=0.f;
    #pragma unroll
    for (int r4=0;r4<4;r4++) {
        float hv = ((const float*)&h4)[r4];
        int i = lane*4 + r4;
        s0 = fmaf(hv, wls[i],     s0);
        s1 = fmaf(hv, wls[256+i], s1);
        s2 = fmaf(hv, wls[512+i], s2);
    }
    #pragma unroll
    for (int off=32; off; off>>=1) {
        s0 += __shfl_down(s0,off); s1 += __shfl_down(s1,off); s2 += __shfl_down(s2,off);
    }
    if (lane == 0) {
        const float* zwl = z_where_last + ((size_t)n*KO + s)*3;
        zwb_all[row*3+0] = fmaxf(s0+bl[0],0.f) + zwl[0];
        zwb_all[row*3+1] = fmaxf(s1+bl[1],0.f) + zwl[1];
        zwb_all[row*3+2] = fmaxf(s2+bl[2],0.f) + zwl[2];
    }
}

__global__ void zero_rin_carry(bf16* __restrict__ rin0) {
    int gid = blockIdx.x*blockDim.x + threadIdx.x;
    if (gid >= NN*309) return;
    int c = gid % 309, n = gid/309;
    int col = (c < 3) ? 103+c : ((c < 53) ? 156+(c-3) : 462+(c-53));
    rin0[(size_t)n*RIN_LD + col] = __float2bfloat16(0.f);
}

// ================= tem LSTM + zwhat + pres (block per n) =================
__global__ __launch_bounds__(256) void tem_fused(
    const float* __restrict__ gates, int nsplit,
    const float* __restrict__ c_r, const float* __restrict__ h_r,
    const float* __restrict__ z_what_last,
    const float* __restrict__ wt_t, const float* __restrict__ bm_wt,
    const float* __restrict__ Wm_pr, const float* __restrict__ bm_pr,
    const float* __restrict__ Ws_pr, const float* __restrict__ bs_pr,
    const float* __restrict__ zw_cur, const float* __restrict__ z_pres_last,
    float* __restrict__ zwhat_cur, float* __restrict__ out_zwhat,
    float* __restrict__ out_htemp, float* __restrict__ out_zpres,
    bf16* __restrict__ rin_next, int k)
{
    __shared__ float L[615];
    __shared__ float part[4][64];
    int n = blockIdx.x, j = threadIdx.x;
    float sI=0.f, sF=0.f, sG=0.f, sO=0.f;
    for (int p = 0; p < nsplit; ++p) {
        const float* g = gates + (size_t)p*GSTR + (size_t)n*1024;
        sI += g[j]; sF += g[256+j]; sG += g[512+j]; sO += g[768+j];
    }
    float ig = sigm(sI), fg = sigm(sF), gg = tanhf(sG), og = sigm(sO);
    float c2 = fg*c_r[n*256+j] + ig*gg;
    float hv = og*tanhf(c2);
    out_htemp[((size_t)n*KO + k)*HIDD + j] = hv;
    L[309+j] = hv;
    L[53+j]  = h_r[n*256+j];
    if (j < 50)      L[j]  = z_what_last[((size_t)n*KO + k)*50 + j];
    else if (j < 53) L[j]  = zw_cur[n*3 + (j-50)];
    __syncthreads();
    {
        int m = j & 63, grp = j >> 6;
        float sa = 0.f;
        for (int i = grp; i < 562; i += 4) {
            float v = (i < 50) ? L[i] : L[i+3];
            sa = fmaf(v, wt_t[i*64 + m], sa);
        }
        part[grp][m] = sa;
    }
    __syncthreads();
    if (j < 50) {
        float acc = part[0][j] + part[1][j] + part[2][j] + part[3][j] + bm_wt[j];
        zwhat_cur[n*50+j] = acc;
        out_zwhat[((size_t)n*KO + k)*50 + j] = acc;
        rin_next[(size_t)n*RIN_LD + 156 + j] = __float2bfloat16(acc);
        L[565+j] = acc;
    }
    __syncthreads();
    if (j < 64) {
        float s1 = 0.f, s2 = 0.f;
        for (int i = j; i < 565; i += 64) {
            float v = (i < 50) ? L[565+i] : L[i];
            s1 = fmaf(v, Wm_pr[i], s1);
            s2 = fmaf(v, Ws_pr[i], s2);
        }
        #pragma unroll
        for (int off = 32; off; off >>= 1) { s1 += __shfl_down(s1,off); s2 += __shfl_down(s2,off); }
        if (j == 0) {
            float p = sigm(s1 + bm_pr[0]) * sigm(s2 + bs_pr[0]);
            out_zpres[(size_t)n*KO + k] = p * z_pres_last[(size_t)n*KO + k];
        }
    }
}

extern "C" void kernel_launch(void* const* d_in, const int* in_sizes, int n_in,
                              void* d_out, int out_size, void* d_ws, size_t ws_size,
                              hipStream_t stream) {
    (void)in_sizes; (void)n_in; (void)out_size;
    const float* img          = (const float*)d_in[0];
    const float* z_what_last  = (const float*)d_in[1];
    const float* z_where_last = (const float*)d_in[2];
    const float* z_pres_last  = (const float*)d_in[3];
    const float* hidden_last  = (const float*)d_in[4];
    const float* W_loca = (const float*)d_in[5];
    const float* b_loca = (const float*)d_in[6];
    const float* Wg     = (const float*)d_in[7];
    const float* bg     = (const float*)d_in[8];
    const float* Wih_rel = (const float*)d_in[9];
    const float* Whh_rel = (const float*)d_in[10];
    const float* bih_rel = (const float*)d_in[11];
    const float* bhh_rel = (const float*)d_in[12];
    const float* Wih_tem = (const float*)d_in[13];
    const float* Whh_tem = (const float*)d_in[14];
    const float* bih_tem = (const float*)d_in[15];
    const float* bhh_tem = (const float*)d_in[16];
    const float* Wm_wh = (const float*)d_in[17];
    const float* bm_wh = (const float*)d_in[18];
    const float* Wm_wt = (const float*)d_in[21];
    const float* bm_wt = (const float*)d_in[22];
    const float* Wm_pr = (const float*)d_in[25];
    const float* bm_pr = (const float*)d_in[26];
    const float* Ws_pr = (const float*)d_in[27];
    const float* bs_pr = (const float*)d_in[28];

    char* base_p = (char*)d_ws;
    size_t off = 0;
    auto carve = [&](size_t bytes) -> char* {
        char* r = base_p + off;
        off += (bytes + 255) & ~(size_t)255;
        return r;
    };
    bf16*  tin      = (bf16*) carve((size_t)NN*TIN_LD*2);
    float* gates    = (float*)carve((size_t)4*NN*1024*4);   // up to 4 split-K partials
    bf16*  W_tem    = (bf16*) carve((size_t)1024*TIN_LD*2);
    bf16*  W_rel    = (bf16*) carve((size_t)1024*RIN_LD*2);
    bf16*  Wg_bf    = (bf16*) carve((size_t)100*G1_LD*2);
    float* wt_t     = (float*)carve((size_t)576*64*4);
    float* zwb_all  = (float*)carve((size_t)KO*NN*3*4);
    float* h_r      = (float*)carve((size_t)NN*HIDD*4);
    float* c_r      = (float*)carve((size_t)NN*HIDD*4);
    float* zw1      = (float*)carve((size_t)NN*3*4);
    float* zwhat1   = (float*)carve((size_t)NN*50*4);
    float* zw0      = (float*)carve((size_t)NN*3*4);
    float* zwhat0   = (float*)carve((size_t)NN*50*4);
    size_t fixed_bytes = off;

    int CH = 1;
    for (int cand : {8, 4, 2}) {
        size_t need = fixed_bytes
                    + (((size_t)cand*NN*G1_LD*2 + 255) & ~(size_t)255)
                    + (((size_t)cand*NN*RIN_LD*2 + 255) & ~(size_t)255);
        if (need <= ws_size) { CH = cand; break; }
    }
    bf16* g1 = nullptr; int g1ld;
    bf16* rin;
    if (CH > 1) {
        g1   = (bf16*)carve((size_t)CH*NN*G1_LD*2);
        rin  = (bf16*)carve((size_t)CH*NN*RIN_LD*2);
        g1ld = G1_LD;
    } else {
        rin  = (bf16*)carve((size_t)NN*RIN_LD*2);
        g1   = tin;
        g1ld = TIN_LD;
    }

    float* out        = (float*)d_out;
    float* out_zwhat  = out;
    float* out_zwhere = out + (size_t)NN*KO*50;
    float* out_zpres  = out_zwhere + (size_t)NN*KO*3;
    float* out_htemp  = out_zpres + (size_t)NN*KO;

    // ---- preamble ----
    {
        int nz = NN*(HIDD + 3 + 50);
        zero_f32<<<(nz+255)/256, 256, 0, stream>>>(c_r, nz);
    }
    zero_rin_carry<<<(NN*309+255)/256, 256, 0, stream>>>(rin);
    repack_w<<<((1024*RIN_LD)+255)/256, 256, 0, stream>>>(Wih_rel, 462, Whh_rel, 256, W_rel, RIN_LD, 1024);
    repack_w<<<((1024*TIN_LD)+255)/256, 256, 0, stream>>>(Wih_tem, 2862, Whh_tem, 256, W_tem, TIN_LD, 1024);
    repack_w<<<((100*G1_LD)+255)/256, 256, 0, stream>>>(Wg, 2500, nullptr, 0, Wg_bf, G1_LD, 100);
    transpose_wmwt<<<(576*64+255)/256, 256, 0, stream>>>(Wm_wt, wt_t);
    zwb_all_v2<<<KO*NN/4, 256, 0, stream>>>(hidden_last, z_where_last, W_loca, b_loca, zwb_all);

    for (int cbase = 0; cbase < KO; cbase += CH) {
        glimpse_all<<<NN, 512, 0, stream>>>(img, zwb_all + (size_t)cbase*NN*3, g1, g1ld,
                                            rin, z_where_last, z_what_last, hidden_last, cbase, CH);
        // enc GEMM (M=100): v4 64² path
        mfma_gemm<1,1><<<dim3(2*CH*32,1), 256, 0, stream>>>(g1, g1ld, G1_LD, Wg_bf, G1_LD, 100,
                                                            bg, nullptr, rin, RIN_LD, 2, G1_LD, 0);

        for (int s = 0; s < CH; ++s) {
            int k = cbase + s;
            bf16* rin_k  = rin + (size_t)s*NN*RIN_LD;
            bf16* rin_nx = rin + (size_t)((s+1)%CH)*NN*RIN_LD;
            float* zw_cur     = (k & 1) ? zw1 : zw0;
            float* zw_prev    = (k & 1) ? zw0 : zw1;
            float* zwhat_cur  = (k & 1) ? zwhat1 : zwhat0;
            float* zwhat_prev = (k & 1) ? zwhat0 : zwhat1;

            // rel LSTM gates: 128x64 tile, split-K=2 -> 512 blocks, 2/CU
            gemm128<2><<<dim3(256,2), 256, 0, stream>>>(rin_k, RIN_LD, RIN_LD, W_rel, RIN_LD,
                                                        bih_rel, bhh_rel, gates, 1024, 16, 384, GSTR);
            rel_glimpse2<<<NN, 256, 0, stream>>>(gates, 2, h_r, c_r, z_where_last, Wm_wh, bm_wh,
                                                 zw_cur, out_zwhere, rin_nx, tin,
                                                 img, zw_prev, zwhat_prev, z_what_last, hidden_last, k);
            // tem LSTM gates: 128x128 tile, split-K=4 -> 512 blocks, 2/CU
            gemm128<4><<<dim3(128,4), 256, 0, stream>>>(tin, TIN_LD, TIN_LD, W_tem, TIN_LD,
                                                        bih_tem, bhh_tem, gates, 1024, 8, 832, GSTR);
            tem_fused<<<NN, 256, 0, stream>>>(gates, 4, c_r, h_r, z_what_last, wt_t, bm_wt, Wm_pr, bm_pr, Ws_pr, bs_pr,
                                              zw_cur, z_pres_last, zwhat_cur, out_zwhat, out_htemp, out_zpres, rin_nx, k);
        }
    }
}